// Round 6
// baseline (411.015 us; speedup 1.0000x reference)
//
#include <hip/hip_runtime.h>
#include <cstdint>
#include <cstddef>

#define SEQL 2048
#define DMODEL 1024
#define DINNER 2048
#define NSTATE 16
#define NC 32          // scan chunks
#define TC 64          // SEQL / NC
#define KS 16          // k_bc split-K chunks
#define KCH 128        // DINNER / KS

typedef __attribute__((ext_vector_type(4))) float f32x4;
typedef __attribute__((ext_vector_type(8))) short short8;
typedef __attribute__((ext_vector_type(4))) short short4v;
typedef unsigned short u16;

__device__ __forceinline__ float b2f(u16 u) {
  union { unsigned int i; float f; } v; v.i = ((unsigned int)u) << 16; return v.f;
}
__device__ __forceinline__ u16 f2b(float f) {
  union { float f; unsigned int i; } v; v.f = f;
  unsigned int r = v.i + 0x7FFFu + ((v.i >> 16) & 1u);
  return (u16)(r >> 16);
}

// ---- transpose + fp32->bf16 : out[c][r] = in[r][c0+c], out is (Cout x R)
__global__ __launch_bounds__(256) void k_transpose_cvt(
    const float* __restrict__ in, u16* __restrict__ out, int R, int C, int c0) {
  __shared__ float t[32][33];
  int cb = blockIdx.x * 32, rb = blockIdx.y * 32;
  int tx = threadIdx.x, ty = threadIdx.y;
#pragma unroll
  for (int i = 0; i < 32; i += 8)
    t[ty + i][tx] = in[(size_t)(rb + ty + i) * C + c0 + cb + tx];
  __syncthreads();
#pragma unroll
  for (int i = 0; i < 32; i += 8)
    out[(size_t)(cb + ty + i) * R + rb + tx] = f2b(t[tx][ty + i]);
}

// ---- LayerNorm over DMODEL, rows = B*L, bf16 in -> bf16 out
__global__ __launch_bounds__(256) void k_layernorm(
    const u16* __restrict__ xt, const float* __restrict__ w,
    const float* __restrict__ b, u16* __restrict__ xn) {
  int row = blockIdx.x;
  const u16* px = xt + (size_t)row * DMODEL;
  int i4 = threadIdx.x * 4;
  short4v sv = *(const short4v*)&px[i4];
  float v[4];
#pragma unroll
  for (int j = 0; j < 4; ++j) v[j] = b2f((u16)sv[j]);
  float s1 = v[0] + v[1] + v[2] + v[3];
  float s2 = v[0]*v[0] + v[1]*v[1] + v[2]*v[2] + v[3]*v[3];
#pragma unroll
  for (int off = 32; off > 0; off >>= 1) {
    s1 += __shfl_xor(s1, off);
    s2 += __shfl_xor(s2, off);
  }
  __shared__ float a1[4], a2[4];
  int lane = threadIdx.x & 63, wid = threadIdx.x >> 6;
  if (lane == 0) { a1[wid] = s1; a2[wid] = s2; }
  __syncthreads();
  float t1 = a1[0] + a1[1] + a1[2] + a1[3];
  float t2 = a2[0] + a2[1] + a2[2] + a2[3];
  float mu = t1 * (1.f / DMODEL);
  float rs = rsqrtf(t2 * (1.f / DMODEL) - mu * mu + 1e-5f);
  short4v ov;
#pragma unroll
  for (int j = 0; j < 4; ++j) ov[j] = (short)f2b((v[j] - mu) * rs * w[i4 + j] + b[i4 + j]);
  *(short4v*)&xn[(size_t)row * DMODEL + i4] = ov;
}

// ==================== 8-phase 256xBN MFMA GEMM ====================
// C[M,N] = A[M,K] * BT[N,K]^T. 512 threads = 8 waves (2 M x 4 N).
// BM=256, BK=64, double-buffered swizzled LDS, counted vmcnt (T3+T4),
// XOR swizzle (T2), setprio around MFMA (T5), XCD-aware block swizzle (T1).
// EPI: 0 = f32 store; 1 = bf16 store; 2 = f32 softplus(acc + bias[col]).
template<int BN, int EPI>
__global__ __launch_bounds__(512) void gemm8p(
    const u16* __restrict__ A, const u16* __restrict__ BT,
    void* __restrict__ outp, const float* __restrict__ bias,
    int M, int N, int K) {
  constexpr int NF  = BN / 64;     // n-frags per wave
  constexpr int NFH = NF / 2;      // n-frags per quadrant
  constexpr int WN  = BN / 4;      // per-wave col span
  constexpr int G   = 16 * NFH;    // B-half row granule
  constexpr int SB  = BN / 128;    // stage instrs per B-half (A-half: 2)
  constexpr int LDSTILE = 64 * (256 + BN);
  __shared__ u16 lds[2 * LDSTILE];

  const int tid = threadIdx.x;
  const int w = tid >> 6, lane = tid & 63;
  const int wm = w >> 2, wn = w & 3;
  const int lg = lane >> 4, lr = lane & 15;
  const int wbase = tid & ~63;

  const int gx = N / BN;
  const int cpx = gridDim.x >> 3;
  const int wg = ((int)blockIdx.x & 7) * cpx + ((int)blockIdx.x >> 3);
  const int tm = (wg / gx) * 256;
  const int tn = (wg % gx) * BN;
  const int NT = K >> 6;

  const u16* Ab = A + (size_t)tm * K;
  const u16* Bb = BT + (size_t)tn * K;

  // stage A-half h of tile tc (rows with bit6==h in each 128-row wm-panel)
  auto stageA = [&](int tc, int h) {
    int tcl = tc < NT ? tc : NT - 1;
    const u16* g0 = Ab + (size_t)tcl * 64;
    u16* l0 = lds + (tc & 1) * LDSTILE;
#pragma unroll
    for (int j = 0; j < 2; ++j) {
      int t8 = j * 512 + tid;
      int r8 = t8 >> 3;                                // 0..127 in half
      int pr = (r8 & 63) + ((r8 >> 6) << 7) + h * 64;  // physical tile row
      int sk = ((((t8 & 7) << 4) ^ ((pr & 7) << 4)) >> 1);
      int r8b = (j * 512 + wbase) >> 3;
      int prb = (r8b & 63) + ((r8b >> 6) << 7) + h * 64;
      __builtin_amdgcn_global_load_lds(
          (const __attribute__((address_space(1))) void*)(g0 + (size_t)pr * K + sk),
          (__attribute__((address_space(3))) void*)(l0 + prb * 64), 16, 0, 0);
    }
  };
  // stage B-half h of tile tc (rows with granule-G parity h in each 2G panel)
  auto stageB = [&](int tc, int h) {
    int tcl = tc < NT ? tc : NT - 1;
    const u16* g0 = Bb + (size_t)tcl * 64;
    u16* l0 = lds + (tc & 1) * LDSTILE + 256 * 64;
#pragma unroll
    for (int j = 0; j < SB; ++j) {
      int t8 = j * 512 + tid;
      int r8 = t8 >> 3;                                  // 0..BN/2-1 in half
      int pr = (r8 % G) + (r8 / G) * 2 * G + h * G;      // physical B row
      int sk = ((((t8 & 7) << 4) ^ ((pr & 7) << 4)) >> 1);
      int r8b = (j * 512 + wbase) >> 3;
      int prb = (r8b % G) + (r8b / G) * 2 * G + h * G;
      __builtin_amdgcn_global_load_lds(
          (const __attribute__((address_space(1))) void*)(g0 + (size_t)pr * K + sk),
          (__attribute__((address_space(3))) void*)(l0 + prb * 64), 16, 0, 0);
    }
  };
  auto fragA = [&](const u16* base, int mf, int kk) -> short8 {
    int r = wm * 128 + mf * 16 + lr;
    int cb = (kk * 64 + lg * 16) ^ ((r & 7) << 4);
    return *(const short8*)((const char*)base + r * 128 + cb);
  };
  auto fragB = [&](const u16* base, int nf, int kk) -> short8 {
    int r = wn * WN + nf * 16 + lr;
    int cb = (kk * 64 + lg * 16) ^ ((r & 7) << 4);
    return *(const short8*)((const char*)base + r * 128 + cb);
  };
  auto vmw = [&]() {  // keep exactly next-2-halves (2+SB instrs) in flight
    if constexpr (SB == 2) asm volatile("s_waitcnt vmcnt(4)" ::: "memory");
    else                   asm volatile("s_waitcnt vmcnt(3)" ::: "memory");
  };

  f32x4 acc[8][NF] = {};
  short8 aF[4][2], bF0[NFH][2], bF1[NFH][2];

  // prologue: tile0 fully + first two halves of tile1
  stageA(0, 0); stageB(0, 0); stageB(0, 1); stageA(0, 1);
  stageA(1, 0); stageB(1, 0);
  vmw();
  __builtin_amdgcn_s_barrier();

  for (int t = 0; t < NT; ++t) {
    const u16* Ac = lds + (t & 1) * LDSTILE;
    const u16* Bc = Ac + 256 * 64;
    // ---- P1: read A-h0 + B-h0, MFMA Q(0,0); stage B1(t+1)
#pragma unroll
    for (int mf = 0; mf < 4; ++mf) { aF[mf][0] = fragA(Ac, mf, 0); aF[mf][1] = fragA(Ac, mf, 1); }
#pragma unroll
    for (int nf = 0; nf < NFH; ++nf) { bF0[nf][0] = fragB(Bc, nf, 0); bF0[nf][1] = fragB(Bc, nf, 1); }
    stageB(t + 1, 1);
    __builtin_amdgcn_s_barrier();
    asm volatile("s_waitcnt lgkmcnt(0)" ::: "memory");
    __builtin_amdgcn_s_setprio(1);
#pragma unroll
    for (int mf = 0; mf < 4; ++mf)
#pragma unroll
      for (int nf = 0; nf < NFH; ++nf) {
        acc[mf][nf] = __builtin_amdgcn_mfma_f32_16x16x32_bf16(aF[mf][0], bF0[nf][0], acc[mf][nf], 0, 0, 0);
        acc[mf][nf] = __builtin_amdgcn_mfma_f32_16x16x32_bf16(aF[mf][1], bF0[nf][1], acc[mf][nf], 0, 0, 0);
      }
    __builtin_amdgcn_s_setprio(0);
    __builtin_amdgcn_s_barrier();
    // ---- P2: read B-h1, MFMA Q(0,1); stage A1(t+1)
#pragma unroll
    for (int nf = 0; nf < NFH; ++nf) { bF1[nf][0] = fragB(Bc, NFH + nf, 0); bF1[nf][1] = fragB(Bc, NFH + nf, 1); }
    stageA(t + 1, 1);
    __builtin_amdgcn_s_barrier();
    asm volatile("s_waitcnt lgkmcnt(0)" ::: "memory");
    __builtin_amdgcn_s_setprio(1);
#pragma unroll
    for (int mf = 0; mf < 4; ++mf)
#pragma unroll
      for (int nf = 0; nf < NFH; ++nf) {
        acc[mf][NFH + nf] = __builtin_amdgcn_mfma_f32_16x16x32_bf16(aF[mf][0], bF1[nf][0], acc[mf][NFH + nf], 0, 0, 0);
        acc[mf][NFH + nf] = __builtin_amdgcn_mfma_f32_16x16x32_bf16(aF[mf][1], bF1[nf][1], acc[mf][NFH + nf], 0, 0, 0);
      }
    __builtin_amdgcn_s_setprio(0);
    __builtin_amdgcn_s_barrier();
    // ---- P3: read A-h1, MFMA Q(1,0); stage A0(t+2)
#pragma unroll
    for (int mf = 0; mf < 4; ++mf) { aF[mf][0] = fragA(Ac, 4 + mf, 0); aF[mf][1] = fragA(Ac, 4 + mf, 1); }
    stageA(t + 2, 0);
    __builtin_amdgcn_s_barrier();
    asm volatile("s_waitcnt lgkmcnt(0)" ::: "memory");
    __builtin_amdgcn_s_setprio(1);
#pragma unroll
    for (int mf = 0; mf < 4; ++mf)
#pragma unroll
      for (int nf = 0; nf < NFH; ++nf) {
        acc[4 + mf][nf] = __builtin_amdgcn_mfma_f32_16x16x32_bf16(aF[mf][0], bF0[nf][0], acc[4 + mf][nf], 0, 0, 0);
        acc[4 + mf][nf] = __builtin_amdgcn_mfma_f32_16x16x32_bf16(aF[mf][1], bF0[nf][1], acc[4 + mf][nf], 0, 0, 0);
      }
    __builtin_amdgcn_s_setprio(0);
    __builtin_amdgcn_s_barrier();
    // ---- P4: MFMA Q(1,1); stage B0(t+2); counted vmcnt
    stageB(t + 2, 0);
    __builtin_amdgcn_s_barrier();
    asm volatile("s_waitcnt lgkmcnt(0)" ::: "memory");
    __builtin_amdgcn_s_setprio(1);
#pragma unroll
    for (int mf = 0; mf < 4; ++mf)
#pragma unroll
      for (int nf = 0; nf < NFH; ++nf) {
        acc[4 + mf][NFH + nf] = __builtin_amdgcn_mfma_f32_16x16x32_bf16(aF[mf][0], bF1[nf][0], acc[4 + mf][NFH + nf], 0, 0, 0);
        acc[4 + mf][NFH + nf] = __builtin_amdgcn_mfma_f32_16x16x32_bf16(aF[mf][1], bF1[nf][1], acc[4 + mf][NFH + nf], 0, 0, 0);
      }
    __builtin_amdgcn_s_setprio(0);
    vmw();
    __builtin_amdgcn_s_barrier();
  }

  // epilogue
#pragma unroll
  for (int mf = 0; mf < 8; ++mf) {
    int r0 = tm + wm * 128 + mf * 16 + lg * 4;
#pragma unroll
    for (int nf = 0; nf < NF; ++nf) {
      int c = tn + wn * WN + nf * 16 + lr;
      f32x4 v = acc[mf][nf];
#pragma unroll
      for (int j = 0; j < 4; ++j) {
        int r = r0 + j;
        if constexpr (EPI == 1) {
          ((u16*)outp)[(size_t)r * N + c] = f2b(v[j]);
        } else if constexpr (EPI == 2) {
          float xv = v[j] + bias[c];
          ((float*)outp)[(size_t)r * N + c] = (xv > 20.f) ? xv : log1pf(__expf(xv));
        } else {
          ((float*)outp)[(size_t)r * N + c] = v[j];
        }
      }
    }
  }
}

// ---- old-style 128x128 MFMA GEMM, kept for EPI 3 (transposed store + residual)
template<int EPI>
__global__ __launch_bounds__(256) void gemm_bf16(
    const u16* __restrict__ A, const u16* __restrict__ BT,
    void* __restrict__ outp, const float* __restrict__ bias,
    const float* __restrict__ resid, int M, int N, int K) {
  __shared__ u16 As[128 * 32];
  __shared__ u16 Bs[128 * 32];
  int tid = threadIdx.x;
  int w = tid >> 6, lane = tid & 63;
  int wr = w >> 1, wc = w & 1;
  int tm = blockIdx.y * 128, tn = blockIdx.x * 128;
  int lg = lane >> 4, lr = lane & 15;
  int srow = lane >> 2;
  int scol = (lane & 3) * 8;

  f32x4 acc[4][4] = {};

  for (int k0 = 0; k0 < K; k0 += 32) {
#pragma unroll
    for (int j = 0; j < 2; ++j) {
      int ch = w * 2 + j;
      const u16* ga = A + (size_t)(tm + ch * 16 + srow) * K + k0 + scol;
      __builtin_amdgcn_global_load_lds(
          (const __attribute__((address_space(1))) void*)ga,
          (__attribute__((address_space(3))) void*)&As[ch * 512], 16, 0, 0);
      const u16* gb = BT + (size_t)(tn + ch * 16 + srow) * K + k0 + scol;
      __builtin_amdgcn_global_load_lds(
          (const __attribute__((address_space(1))) void*)gb,
          (__attribute__((address_space(3))) void*)&Bs[ch * 512], 16, 0, 0);
    }
    __syncthreads();
    short8 aF[4], bF[4];
#pragma unroll
    for (int m = 0; m < 4; ++m)
      aF[m] = *(const short8*)&As[(wr * 64 + m * 16 + lr) * 32 + lg * 8];
#pragma unroll
    for (int n = 0; n < 4; ++n)
      bF[n] = *(const short8*)&Bs[(wc * 64 + n * 16 + lr) * 32 + lg * 8];
#pragma unroll
    for (int m = 0; m < 4; ++m)
#pragma unroll
      for (int n = 0; n < 4; ++n)
        acc[m][n] = __builtin_amdgcn_mfma_f32_16x16x32_bf16(aF[m], bF[n], acc[m][n], 0, 0, 0);
    __syncthreads();
  }

#pragma unroll
  for (int m = 0; m < 4; ++m) {
    int r0 = tm + wr * 64 + m * 16 + lg * 4;
#pragma unroll
    for (int n = 0; n < 4; ++n) {
      int c = tn + wc * 64 + n * 16 + lr;
      f32x4 v = acc[m][n];
#pragma unroll
      for (int j = 0; j < 4; ++j) {
        int r = r0 + j;
        if (EPI == 0) {
          ((float*)outp)[(size_t)r * N + c] = v[j];
        } else if (EPI == 1) {
          ((u16*)outp)[(size_t)r * N + c] = f2b(v[j]);
        } else if (EPI == 2) {
          float xv = v[j] + bias[c];
          ((float*)outp)[(size_t)r * N + c] = (xv > 20.f) ? xv : log1pf(__expf(xv));
        } else {
          int bb = r >> 11, t = r & (SEQL - 1);
          size_t oi = ((size_t)(bb * N + c)) * SEQL + t;
          ((float*)outp)[oi] = v[j] + resid[oi];
        }
      }
    }
  }
}

// ---- depthwise causal conv(k=4) + bias + silu; reads bf16 xz[...,0:2048]
__global__ __launch_bounds__(256) void k_conv_silu(
    const u16* __restrict__ xz, const float* __restrict__ cw,
    const float* __restrict__ cb, u16* __restrict__ xbt) {
  size_t idx = (size_t)blockIdx.x * 256 + threadIdx.x;  // B*L*DINNER threads
  int d = (int)(idx & (DINNER - 1));
  int l = (int)((idx >> 11) & (SEQL - 1));
  int b = (int)(idx >> 22);
  f32x4 w = *(const f32x4*)&cw[d * 4];
  float acc = cb[d];
  size_t base = ((size_t)b * SEQL) * 4096 + d;
#pragma unroll
  for (int i = 0; i < 4; ++i) {
    int ls = l - 3 + i;
    if (ls >= 0) acc += w[i] * b2f(xz[base + (size_t)ls * 4096]);
  }
  float s = acc / (1.f + __expf(-acc));
  xbt[idx] = f2b(s);
}

// ---- split-K MFMA skinny GEMM: bcp[ks][r][j] = sum_{k in chunk} xbt[r,k]*WxBCT[j,k]
__global__ __launch_bounds__(256) void k_bc_mfma(
    const u16* __restrict__ xbt, const u16* __restrict__ WxBCT,
    float* __restrict__ bcp) {
  __shared__ u16 As[128 * 32];
  int tid = threadIdx.x;
  int w = tid >> 6, lane = tid & 63;
  int tm = blockIdx.x * 128;
  int k0 = blockIdx.y * KCH;
  int lg = lane >> 4, lr = lane & 15;
  int srow = lane >> 2, scol = (lane & 3) * 8;

  f32x4 acc[2][2] = {};

  for (int kk = k0; kk < k0 + KCH; kk += 32) {
#pragma unroll
    for (int j = 0; j < 2; ++j) {
      int ch = w * 2 + j;
      const u16* ga = xbt + (size_t)(tm + ch * 16 + srow) * DINNER + kk + scol;
      __builtin_amdgcn_global_load_lds(
          (const __attribute__((address_space(1))) void*)ga,
          (__attribute__((address_space(3))) void*)&As[ch * 512], 16, 0, 0);
    }
    __syncthreads();
    short8 aF[2], bF[2];
#pragma unroll
    for (int m = 0; m < 2; ++m)
      aF[m] = *(const short8*)&As[(w * 32 + m * 16 + lr) * 32 + lg * 8];
#pragma unroll
    for (int n = 0; n < 2; ++n)
      bF[n] = *(const short8*)&WxBCT[(size_t)(n * 16 + lr) * DINNER + kk + lg * 8];
#pragma unroll
    for (int m = 0; m < 2; ++m)
#pragma unroll
      for (int n = 0; n < 2; ++n)
        acc[m][n] = __builtin_amdgcn_mfma_f32_16x16x32_bf16(aF[m], bF[n], acc[m][n], 0, 0, 0);
    __syncthreads();
  }

  float* outp = bcp + (size_t)blockIdx.y * (4096 * 32);
#pragma unroll
  for (int m = 0; m < 2; ++m) {
    int r0 = tm + w * 32 + m * 16 + lg * 4;
#pragma unroll
    for (int n = 0; n < 2; ++n) {
      int c = n * 16 + lr;
      f32x4 v = acc[m][n];
#pragma unroll
      for (int j = 0; j < 4; ++j)
        outp[(size_t)(r0 + j) * 32 + c] = v[j];
    }
  }
}

// ---- reduce split-K partials
__global__ __launch_bounds__(256) void k_bc_red(
    const float* __restrict__ bcp, float* __restrict__ bc) {
  size_t i = (size_t)blockIdx.x * 256 + threadIdx.x;
  float s = 0.f;
#pragma unroll
  for (int ks = 0; ks < KS; ++ks)
    s += bcp[(size_t)ks * (4096 * 32) + i];
  bc[i] = s;
}

// ==== chunked selective scan ====
__global__ __launch_bounds__(256) void k_scan_p1(
    const float* __restrict__ dlt, const u16* __restrict__ ub,
    const float* __restrict__ bcv, const float* __restrict__ A_log,
    float* __restrict__ Pc, float* __restrict__ Qc) {
  int d = blockIdx.x * 256 + threadIdx.x;
  int c = blockIdx.y;
  int b = blockIdx.z;
  float Av[16];
#pragma unroll
  for (int sv = 0; sv < 4; ++sv) {
    f32x4 al = *(const f32x4*)&A_log[d * 16 + sv * 4];
#pragma unroll
    for (int j = 0; j < 4; ++j) Av[sv * 4 + j] = -__expf(al[j]);
  }
  float P[16], Q[16];
#pragma unroll
  for (int s = 0; s < 16; ++s) { P[s] = 1.f; Q[s] = 0.f; }
  size_t row0 = (size_t)b * SEQL + (size_t)c * TC;
  for (int t = 0; t < TC; ++t) {
    size_t row = row0 + t;
    float dl = dlt[row * DINNER + d];
    float uu = b2f(ub[row * DINNER + d]);
    float bco = dl * uu;
    const f32x4* Bp = (const f32x4*)&bcv[row * 32];
#pragma unroll
    for (int sv = 0; sv < 4; ++sv) {
      f32x4 Bv = Bp[sv];
#pragma unroll
      for (int j = 0; j < 4; ++j) {
        int s = sv * 4 + j;
        float dA = __expf(dl * Av[s]);
        P[s] *= dA;
        Q[s] = dA * Q[s] + bco * Bv[j];
      }
    }
  }
  size_t base = (((size_t)b * NC + c) * DINNER + d) * 16;
#pragma unroll
  for (int sv = 0; sv < 4; ++sv) {
    f32x4 pv, qv;
#pragma unroll
    for (int j = 0; j < 4; ++j) { pv[j] = P[sv * 4 + j]; qv[j] = Q[sv * 4 + j]; }
    *(f32x4*)&Pc[base + sv * 4] = pv;
    *(f32x4*)&Qc[base + sv * 4] = qv;
  }
}

__global__ __launch_bounds__(256) void k_scan_p2(
    const float* __restrict__ Pc, const float* __restrict__ Qc,
    float* __restrict__ Hs) {
  size_t gid = (size_t)blockIdx.x * 256 + threadIdx.x;
  size_t bds = gid & ((size_t)DINNER * 16 - 1);
  int b = (int)(gid >> 15);
  float h = 0.f;
  size_t cstride = (size_t)DINNER * 16;
  size_t base = (size_t)b * NC * cstride + bds;
  for (int c = 0; c < NC; ++c) {
    size_t idx = base + (size_t)c * cstride;
    Hs[idx] = h;
    h = Pc[idx] * h + Qc[idx];
  }
}

__global__ __launch_bounds__(256) void k_scan_p3(
    const float* __restrict__ dlt, const u16* __restrict__ ub,
    const float* __restrict__ bcv, const u16* __restrict__ xz,
    const float* __restrict__ A_log, const float* __restrict__ Dskip,
    const float* __restrict__ Hs, u16* __restrict__ yg) {
  int d = blockIdx.x * 256 + threadIdx.x;
  int c = blockIdx.y;
  int b = blockIdx.z;
  float Av[16];
#pragma unroll
  for (int sv = 0; sv < 4; ++sv) {
    f32x4 al = *(const f32x4*)&A_log[d * 16 + sv * 4];
#pragma unroll
    for (int j = 0; j < 4; ++j) Av[sv * 4 + j] = -__expf(al[j]);
  }
  float h[16];
  size_t hb = (((size_t)b * NC + c) * DINNER + d) * 16;
#pragma unroll
  for (int sv = 0; sv < 4; ++sv) {
    f32x4 hv = *(const f32x4*)&Hs[hb + sv * 4];
#pragma unroll
    for (int j = 0; j < 4; ++j) h[sv * 4 + j] = hv[j];
  }
  float Dsk = Dskip[d];
  size_t row0 = (size_t)b * SEQL + (size_t)c * TC;
  for (int t = 0; t < TC; ++t) {
    size_t row = row0 + t;
    float dl = dlt[row * DINNER + d];
    float uu = b2f(ub[row * DINNER + d]);
    float bco = dl * uu;
    const f32x4* BCp = (const f32x4*)&bcv[row * 32];
    float y = 0.f;
#pragma unroll
    for (int sv = 0; sv < 4; ++sv) {
      f32x4 Bv = BCp[sv];
      f32x4 Cv = BCp[4 + sv];
#pragma unroll
      for (int j = 0; j < 4; ++j) {
        int s = sv * 4 + j;
        float dA = __expf(dl * Av[s]);
        h[s] = dA * h[s] + bco * Bv[j];
        y += h[s] * Cv[j];
      }
    }
    float zv = b2f(xz[row * 4096 + DINNER + d]);
    float yv = (y + Dsk * uu) * (zv / (1.f + __expf(-zv)));
    yg[row * DINNER + d] = f2b(yv);
  }
}

extern "C" void kernel_launch(void* const* d_in, const int* in_sizes, int n_in,
                              void* d_out, int out_size, void* d_ws, size_t ws_size,
                              hipStream_t stream) {
  (void)in_sizes; (void)n_in; (void)out_size; (void)ws_size;
  const float* x      = (const float*)d_in[0];
  const float* ln_w   = (const float*)d_in[1];
  const float* ln_b   = (const float*)d_in[2];
  const float* W_in   = (const float*)d_in[3];
  const float* conv_w = (const float*)d_in[4];
  const float* conv_b = (const float*)d_in[5];
  const float* W_x    = (const float*)d_in[6];
  const float* W_dt   = (const float*)d_in[7];
  const float* b_dt   = (const float*)d_in[8];
  const float* A_log  = (const float*)d_in[9];
  const float* Dskip  = (const float*)d_in[10];
  const float* W_out  = (const float*)d_in[11];
  float* out = (float*)d_out;

  char* ws = (char*)d_ws;
  const size_t MB = 1048576;
  u16*  xt    = (u16*)(ws + 0 * MB);     //  8 MB bf16 (B,L,DMODEL); dead after LN
  u16*  xn    = (u16*)(ws + 8 * MB);     //  8 MB bf16; dead after gemm<0>
  u16*  WinT  = (u16*)(ws + 16 * MB);    //  8 MB bf16 (4096,1024)
  u16*  WxT   = (u16*)(ws + 24 * MB);    //  8 MB bf16 (2048,2048)
  u16*  WdtT  = (u16*)(ws + 32 * MB);    //  8 MB bf16 (2048,2048)
  u16*  WoutT = (u16*)(ws + 40 * MB);    //  4 MB bf16 (1024,2048)
  u16*  xz    = (u16*)(ws + 44 * MB);    // 32 MB bf16 (B*L, 4096)
  u16*  xbt   = (u16*)(ws + 76 * MB);    // 16 MB bf16 (B*L, DINNER)
  float* bc   = (float*)(ws + 92 * MB);  // 0.5 MB f32 (B*L, 32)
  u16*  dtin  = (u16*)(ws + 93 * MB);    // 16 MB bf16
  float* dlt  = (float*)(ws + 109 * MB); // 32 MB f32 (B*L, DINNER)
  float* Pc   = (float*)(ws + 141 * MB); //  8 MB
  float* Qc   = (float*)(ws + 149 * MB); //  8 MB
  float* Hs   = (float*)(ws + 157 * MB); //  8 MB
  float* bcp  = (float*)(ws + 165 * MB); //  8 MB split-K partials
  u16*  WxBCT = (u16*)(ws + 173 * MB);   // 128 KB bf16 (32,2048)
  u16*  yg    = (u16*)(ws + 0 * MB);     // 16 MB bf16, aliases xt+xn (dead)

  dim3 tb(32, 8);
  for (int b = 0; b < 2; ++b)
    k_transpose_cvt<<<dim3(SEQL / 32, DMODEL / 32), tb, 0, stream>>>(
        x + (size_t)b * DMODEL * SEQL, xt + (size_t)b * SEQL * DMODEL, DMODEL, SEQL, 0);
  k_transpose_cvt<<<dim3(4096 / 32, 1024 / 32), tb, 0, stream>>>(W_in, WinT, 1024, 4096, 0);
  k_transpose_cvt<<<dim3(2048 / 32, 2048 / 32), tb, 0, stream>>>(W_x, WxT, 2048, 2080, 32);
  k_transpose_cvt<<<dim3(1, 2048 / 32), tb, 0, stream>>>(W_x, WxBCT, 2048, 2080, 0);
  k_transpose_cvt<<<dim3(2048 / 32, 2048 / 32), tb, 0, stream>>>(W_dt, WdtT, 2048, 2048, 0);
  k_transpose_cvt<<<dim3(1024 / 32, 2048 / 32), tb, 0, stream>>>(W_out, WoutT, 2048, 1024, 0);

  k_layernorm<<<4096, 256, 0, stream>>>(xt, ln_w, ln_b, xn);

  // xz = xn @ W_in   (4096 x 4096, K=1024), bf16 out  -- 256 blocks
  gemm8p<256, 1><<<256, 512, 0, stream>>>(xn, WinT, xz, nullptr, 4096, 4096, 1024);

  k_conv_silu<<<32768, 256, 0, stream>>>(xz, conv_w, conv_b, xbt);

  // bc = xbt @ W_x[:, :32]
  k_bc_mfma<<<dim3(4096 / 128, KS), 256, 0, stream>>>(xbt, WxBCT, bcp);
  k_bc_red<<<131072 / 256, 256, 0, stream>>>(bcp, bc);

  // dtin = xbt @ W_x[:,32:]  (bf16 out) -- 128 blocks
  gemm8p<256, 1><<<128, 512, 0, stream>>>(xbt, WxT, dtin, nullptr, 4096, 2048, 2048);

  // dlt = softplus(dtin @ W_dt + b_dt)  (f32 out) -- 128 blocks
  gemm8p<256, 2><<<128, 512, 0, stream>>>(dtin, WdtT, dlt, b_dt, 4096, 2048, 2048);

  // chunked scan
  k_scan_p1<<<dim3(DINNER / 256, NC, 2), 256, 0, stream>>>(dlt, xbt, bc, A_log, Pc, Qc);
  k_scan_p2<<<256, 256, 0, stream>>>(Pc, Qc, Hs);
  k_scan_p3<<<dim3(DINNER / 256, NC, 2), 256, 0, stream>>>(
      dlt, xbt, bc, xz, A_log, Dskip, Hs, yg);

  // out = yg @ W_out, transposed store + residual
  gemm_bf16<3><<<dim3(1024 / 128, 4096 / 128), 256, 0, stream>>>(
      yg, WoutT, out, nullptr, x, 4096, 1024, 2048);
}

// Round 7
// 334.997 us; speedup vs baseline: 1.2269x; 1.2269x over previous
//
#include <hip/hip_runtime.h>
#include <cstdint>
#include <cstddef>

#define SEQL 2048
#define DMODEL 1024
#define DINNER 2048
#define NSTATE 16
#define NC 32          // scan chunks
#define TC 64          // SEQL / NC
#define KS 16          // k_bc split-K chunks
#define KCH 128        // DINNER / KS

typedef __attribute__((ext_vector_type(4))) float f32x4;
typedef __attribute__((ext_vector_type(8))) short short8;
typedef __attribute__((ext_vector_type(4))) short short4v;
typedef unsigned short u16;

__device__ __forceinline__ float b2f(u16 u) {
  union { unsigned int i; float f; } v; v.i = ((unsigned int)u) << 16; return v.f;
}
__device__ __forceinline__ u16 f2b(float f) {
  union { float f; unsigned int i; } v; v.f = f;
  unsigned int r = v.i + 0x7FFFu + ((v.i >> 16) & 1u);
  return (u16)(r >> 16);
}

// ---- transpose + fp32->bf16 : out[c][r] = in[r][c0+c], out is (Cout x R)
__global__ __launch_bounds__(256) void k_transpose_cvt(
    const float* __restrict__ in, u16* __restrict__ out, int R, int C, int c0) {
  __shared__ float t[32][33];
  int cb = blockIdx.x * 32, rb = blockIdx.y * 32;
  int tx = threadIdx.x, ty = threadIdx.y;
#pragma unroll
  for (int i = 0; i < 32; i += 8)
    t[ty + i][tx] = in[(size_t)(rb + ty + i) * C + c0 + cb + tx];
  __syncthreads();
#pragma unroll
  for (int i = 0; i < 32; i += 8)
    out[(size_t)(cb + ty + i) * R + rb + tx] = f2b(t[tx][ty + i]);
}

// ---- LayerNorm over DMODEL, rows = B*L, bf16 in -> bf16 out
__global__ __launch_bounds__(256) void k_layernorm(
    const u16* __restrict__ xt, const float* __restrict__ w,
    const float* __restrict__ b, u16* __restrict__ xn) {
  int row = blockIdx.x;
  const u16* px = xt + (size_t)row * DMODEL;
  int i4 = threadIdx.x * 4;
  short4v sv = *(const short4v*)&px[i4];
  float v[4];
#pragma unroll
  for (int j = 0; j < 4; ++j) v[j] = b2f((u16)sv[j]);
  float s1 = v[0] + v[1] + v[2] + v[3];
  float s2 = v[0]*v[0] + v[1]*v[1] + v[2]*v[2] + v[3]*v[3];
#pragma unroll
  for (int off = 32; off > 0; off >>= 1) {
    s1 += __shfl_xor(s1, off);
    s2 += __shfl_xor(s2, off);
  }
  __shared__ float a1[4], a2[4];
  int lane = threadIdx.x & 63, wid = threadIdx.x >> 6;
  if (lane == 0) { a1[wid] = s1; a2[wid] = s2; }
  __syncthreads();
  float t1 = a1[0] + a1[1] + a1[2] + a1[3];
  float t2 = a2[0] + a2[1] + a2[2] + a2[3];
  float mu = t1 * (1.f / DMODEL);
  float rs = rsqrtf(t2 * (1.f / DMODEL) - mu * mu + 1e-5f);
  short4v ov;
#pragma unroll
  for (int j = 0; j < 4; ++j) ov[j] = (short)f2b((v[j] - mu) * rs * w[i4 + j] + b[i4 + j]);
  *(short4v*)&xn[(size_t)row * DMODEL + i4] = ov;
}

// ==================== 4-phase 128x128 MFMA GEMM, 2 blocks/CU ====================
// C[M,N] = A[M,K] * BT[N,K]^T. 256 threads = 4 waves (2 M x 2 N), BK=64,
// double-buffered swizzled LDS (64 KiB -> 2 blocks/CU for inter-block overlap),
// counted vmcnt, XOR swizzle, setprio, XCD-aware block swizzle.
// EPI: 0 = f32 store; 1 = bf16 store; 2 = f32 softplus(acc + bias[col]);
//      3 = transposed store + residual: out[(b*N+c)*SEQL+t] = acc + resid[..]
template<int EPI>
__global__ __launch_bounds__(256) void gemm8p(
    const u16* __restrict__ A, const u16* __restrict__ BT,
    void* __restrict__ outp, const float* __restrict__ bias,
    const float* __restrict__ resid, int M, int N, int K) {
  constexpr int LDSTILE = 2 * 128 * 64;   // A(128x64) + B(128x64) elems
  __shared__ u16 lds[2 * LDSTILE];        // 64 KiB

  const int tid = threadIdx.x;
  const int w = tid >> 6, lane = tid & 63;
  const int wm = w >> 1, wn = w & 1;
  const int lg = lane >> 4, lr = lane & 15;
  const int wbase = tid & ~63;

  const int gx = N / 128;
  const int cpx = gridDim.x >> 3;
  const int wg = ((int)blockIdx.x & 7) * cpx + ((int)blockIdx.x >> 3);
  const int tm = (wg / gx) * 128;
  const int tn = (wg % gx) * 128;
  const int NT = K >> 6;

  const u16* Ab = A + (size_t)tm * K;
  const u16* Bb = BT + (size_t)tn * K;

  // stage half h (32 rows per 64-row wave-panel) of A or B for tile tc.
  // 2 x global_load_lds per call (64 rows x 128B = 8 KB = 512 lanes x 16B).
  auto stage = [&](const u16* gbase, int boff, int tc, int h) {
    int tcl = tc < NT ? tc : NT - 1;
    const u16* g0 = gbase + (size_t)tcl * 64;
    u16* l0 = lds + (tc & 1) * LDSTILE + boff;
#pragma unroll
    for (int j = 0; j < 2; ++j) {
      int t8 = j * 256 + tid;
      int r8 = t8 >> 3;                                // 0..63 within half
      int pr = (r8 & 31) + ((r8 >> 5) << 6) + h * 32;  // physical tile row
      int sk = ((((t8 & 7) << 4) ^ ((pr & 7) << 4)) >> 1);
      int r8b = (j * 256 + wbase) >> 3;
      int prb = (r8b & 31) + ((r8b >> 5) << 6) + h * 32;
      __builtin_amdgcn_global_load_lds(
          (const __attribute__((address_space(1))) void*)(g0 + (size_t)pr * K + sk),
          (__attribute__((address_space(3))) void*)(l0 + prb * 64), 16, 0, 0);
    }
  };
  auto fragA = [&](int buf, int mf, int kk) -> short8 {
    int r = wm * 64 + mf * 16 + lr;
    int cb = (kk * 64 + lg * 16) ^ ((r & 7) << 4);
    return *(const short8*)((const char*)(lds + buf * LDSTILE) + r * 128 + cb);
  };
  auto fragB = [&](int buf, int nf, int kk) -> short8 {
    int r = wn * 64 + nf * 16 + lr;
    int cb = (kk * 64 + lg * 16) ^ ((r & 7) << 4);
    return *(const short8*)((const char*)(lds + buf * LDSTILE + 128 * 64) + r * 128 + cb);
  };

  f32x4 acc[4][4] = {};
  short8 aF[2][2], bF0[2][2], bF1[2][2];

  // prologue: tile0 fully + first two halves of tile1 (12 loads; drain 8)
  stage(Ab, 0, 0, 0); stage(Bb, 128 * 64, 0, 0);
  stage(Bb, 128 * 64, 0, 1); stage(Ab, 0, 0, 1);
  stage(Ab, 0, 1, 0); stage(Bb, 128 * 64, 1, 0);
  asm volatile("s_waitcnt vmcnt(4)" ::: "memory");
  __builtin_amdgcn_s_barrier();

  for (int t = 0; t < NT; ++t) {
    const int buf = t & 1;
    // ---- P1: read A-h0 + B-h0, MFMA (mf01 x nf01); stage B-h1(t+1)
#pragma unroll
    for (int mf = 0; mf < 2; ++mf) { aF[mf][0] = fragA(buf, mf, 0); aF[mf][1] = fragA(buf, mf, 1); }
#pragma unroll
    for (int nf = 0; nf < 2; ++nf) { bF0[nf][0] = fragB(buf, nf, 0); bF0[nf][1] = fragB(buf, nf, 1); }
    stage(Bb, 128 * 64, t + 1, 1);
    __builtin_amdgcn_s_barrier();
    asm volatile("s_waitcnt lgkmcnt(0)" ::: "memory");
    __builtin_amdgcn_s_setprio(1);
#pragma unroll
    for (int mf = 0; mf < 2; ++mf)
#pragma unroll
      for (int nf = 0; nf < 2; ++nf) {
        acc[mf][nf] = __builtin_amdgcn_mfma_f32_16x16x32_bf16(aF[mf][0], bF0[nf][0], acc[mf][nf], 0, 0, 0);
        acc[mf][nf] = __builtin_amdgcn_mfma_f32_16x16x32_bf16(aF[mf][1], bF0[nf][1], acc[mf][nf], 0, 0, 0);
      }
    __builtin_amdgcn_s_setprio(0);
    __builtin_amdgcn_s_barrier();
    // ---- P2: read B-h1, MFMA (mf01 x nf23); stage A-h1(t+1)
#pragma unroll
    for (int nf = 0; nf < 2; ++nf) { bF1[nf][0] = fragB(buf, 2 + nf, 0); bF1[nf][1] = fragB(buf, 2 + nf, 1); }
    stage(Ab, 0, t + 1, 1);
    __builtin_amdgcn_s_barrier();
    asm volatile("s_waitcnt lgkmcnt(0)" ::: "memory");
    __builtin_amdgcn_s_setprio(1);
#pragma unroll
    for (int mf = 0; mf < 2; ++mf)
#pragma unroll
      for (int nf = 0; nf < 2; ++nf) {
        acc[mf][2 + nf] = __builtin_amdgcn_mfma_f32_16x16x32_bf16(aF[mf][0], bF1[nf][0], acc[mf][2 + nf], 0, 0, 0);
        acc[mf][2 + nf] = __builtin_amdgcn_mfma_f32_16x16x32_bf16(aF[mf][1], bF1[nf][1], acc[mf][2 + nf], 0, 0, 0);
      }
    __builtin_amdgcn_s_setprio(0);
    __builtin_amdgcn_s_barrier();
    // ---- P3: read A-h1, MFMA (mf23 x nf01); stage A-h0(t+2)
#pragma unroll
    for (int mf = 0; mf < 2; ++mf) { aF[mf][0] = fragA(buf, 2 + mf, 0); aF[mf][1] = fragA(buf, 2 + mf, 1); }
    stage(Ab, 0, t + 2, 0);
    __builtin_amdgcn_s_barrier();
    asm volatile("s_waitcnt lgkmcnt(0)" ::: "memory");
    __builtin_amdgcn_s_setprio(1);
#pragma unroll
    for (int mf = 0; mf < 2; ++mf)
#pragma unroll
      for (int nf = 0; nf < 2; ++nf) {
        acc[2 + mf][nf] = __builtin_amdgcn_mfma_f32_16x16x32_bf16(aF[mf][0], bF0[nf][0], acc[2 + mf][nf], 0, 0, 0);
        acc[2 + mf][nf] = __builtin_amdgcn_mfma_f32_16x16x32_bf16(aF[mf][1], bF0[nf][1], acc[2 + mf][nf], 0, 0, 0);
      }
    __builtin_amdgcn_s_setprio(0);
    __builtin_amdgcn_s_barrier();
    // ---- P4: MFMA (mf23 x nf23); stage B-h0(t+2); counted vmcnt
    stage(Bb, 128 * 64, t + 2, 0);
    __builtin_amdgcn_s_barrier();
    asm volatile("s_waitcnt lgkmcnt(0)" ::: "memory");
    __builtin_amdgcn_s_setprio(1);
#pragma unroll
    for (int mf = 0; mf < 2; ++mf)
#pragma unroll
      for (int nf = 0; nf < 2; ++nf) {
        acc[2 + mf][2 + nf] = __builtin_amdgcn_mfma_f32_16x16x32_bf16(aF[mf][0], bF1[nf][0], acc[2 + mf][2 + nf], 0, 0, 0);
        acc[2 + mf][2 + nf] = __builtin_amdgcn_mfma_f32_16x16x32_bf16(aF[mf][1], bF1[nf][1], acc[2 + mf][2 + nf], 0, 0, 0);
      }
    __builtin_amdgcn_s_setprio(0);
    asm volatile("s_waitcnt vmcnt(4)" ::: "memory");
    __builtin_amdgcn_s_barrier();
  }

  // epilogue
#pragma unroll
  for (int mf = 0; mf < 4; ++mf) {
    int r0 = tm + wm * 64 + mf * 16 + lg * 4;
#pragma unroll
    for (int nf = 0; nf < 4; ++nf) {
      int c = tn + wn * 64 + nf * 16 + lr;
      f32x4 v = acc[mf][nf];
#pragma unroll
      for (int j = 0; j < 4; ++j) {
        int r = r0 + j;
        if constexpr (EPI == 1) {
          ((u16*)outp)[(size_t)r * N + c] = f2b(v[j]);
        } else if constexpr (EPI == 2) {
          float xv = v[j] + bias[c];
          ((float*)outp)[(size_t)r * N + c] = (xv > 20.f) ? xv : log1pf(__expf(xv));
        } else if constexpr (EPI == 3) {
          int bb = r >> 11, tt = r & (SEQL - 1);
          size_t oi = ((size_t)(bb * N + c)) * SEQL + tt;
          ((float*)outp)[oi] = v[j] + resid[oi];
        } else {
          ((float*)outp)[(size_t)r * N + c] = v[j];
        }
      }
    }
  }
}

// ---- depthwise causal conv(k=4) + bias + silu; reads bf16 xz[...,0:2048]
__global__ __launch_bounds__(256) void k_conv_silu(
    const u16* __restrict__ xz, const float* __restrict__ cw,
    const float* __restrict__ cb, u16* __restrict__ xbt) {
  size_t idx = (size_t)blockIdx.x * 256 + threadIdx.x;  // B*L*DINNER threads
  int d = (int)(idx & (DINNER - 1));
  int l = (int)((idx >> 11) & (SEQL - 1));
  int b = (int)(idx >> 22);
  f32x4 w = *(const f32x4*)&cw[d * 4];
  float acc = cb[d];
  size_t base = ((size_t)b * SEQL) * 4096 + d;
#pragma unroll
  for (int i = 0; i < 4; ++i) {
    int ls = l - 3 + i;
    if (ls >= 0) acc += w[i] * b2f(xz[base + (size_t)ls * 4096]);
  }
  float s = acc / (1.f + __expf(-acc));
  xbt[idx] = f2b(s);
}

// ---- split-K MFMA skinny GEMM: bcp[ks][r][j] = sum_{k in chunk} xbt[r,k]*WxBCT[j,k]
__global__ __launch_bounds__(256) void k_bc_mfma(
    const u16* __restrict__ xbt, const u16* __restrict__ WxBCT,
    float* __restrict__ bcp) {
  __shared__ u16 As[128 * 32];
  int tid = threadIdx.x;
  int w = tid >> 6, lane = tid & 63;
  int tm = blockIdx.x * 128;
  int k0 = blockIdx.y * KCH;
  int lg = lane >> 4, lr = lane & 15;
  int srow = lane >> 2, scol = (lane & 3) * 8;

  f32x4 acc[2][2] = {};

  for (int kk = k0; kk < k0 + KCH; kk += 32) {
#pragma unroll
    for (int j = 0; j < 2; ++j) {
      int ch = w * 2 + j;
      const u16* ga = xbt + (size_t)(tm + ch * 16 + srow) * DINNER + kk + scol;
      __builtin_amdgcn_global_load_lds(
          (const __attribute__((address_space(1))) void*)ga,
          (__attribute__((address_space(3))) void*)&As[ch * 512], 16, 0, 0);
    }
    __syncthreads();
    short8 aF[2], bF[2];
#pragma unroll
    for (int m = 0; m < 2; ++m)
      aF[m] = *(const short8*)&As[(w * 32 + m * 16 + lr) * 32 + lg * 8];
#pragma unroll
    for (int n = 0; n < 2; ++n)
      bF[n] = *(const short8*)&WxBCT[(size_t)(n * 16 + lr) * DINNER + kk + lg * 8];
#pragma unroll
    for (int m = 0; m < 2; ++m)
#pragma unroll
      for (int n = 0; n < 2; ++n)
        acc[m][n] = __builtin_amdgcn_mfma_f32_16x16x32_bf16(aF[m], bF[n], acc[m][n], 0, 0, 0);
    __syncthreads();
  }

  float* outp = bcp + (size_t)blockIdx.y * (4096 * 32);
#pragma unroll
  for (int m = 0; m < 2; ++m) {
    int r0 = tm + w * 32 + m * 16 + lg * 4;
#pragma unroll
    for (int n = 0; n < 2; ++n) {
      int c = n * 16 + lr;
      f32x4 v = acc[m][n];
#pragma unroll
      for (int j = 0; j < 4; ++j)
        outp[(size_t)(r0 + j) * 32 + c] = v[j];
    }
  }
}

// ---- reduce split-K partials
__global__ __launch_bounds__(256) void k_bc_red(
    const float* __restrict__ bcp, float* __restrict__ bc) {
  size_t i = (size_t)blockIdx.x * 256 + threadIdx.x;
  float s = 0.f;
#pragma unroll
  for (int ks = 0; ks < KS; ++ks)
    s += bcp[(size_t)ks * (4096 * 32) + i];
  bc[i] = s;
}

// ==== chunked selective scan ====
__global__ __launch_bounds__(256) void k_scan_p1(
    const float* __restrict__ dlt, const u16* __restrict__ ub,
    const float* __restrict__ bcv, const float* __restrict__ A_log,
    float* __restrict__ Pc, float* __restrict__ Qc) {
  int d = blockIdx.x * 256 + threadIdx.x;
  int c = blockIdx.y;
  int b = blockIdx.z;
  float Av[16];
#pragma unroll
  for (int sv = 0; sv < 4; ++sv) {
    f32x4 al = *(const f32x4*)&A_log[d * 16 + sv * 4];
#pragma unroll
    for (int j = 0; j < 4; ++j) Av[sv * 4 + j] = -__expf(al[j]);
  }
  float P[16], Q[16];
#pragma unroll
  for (int s = 0; s < 16; ++s) { P[s] = 1.f; Q[s] = 0.f; }
  size_t row0 = (size_t)b * SEQL + (size_t)c * TC;
  for (int t = 0; t < TC; ++t) {
    size_t row = row0 + t;
    float dl = dlt[row * DINNER + d];
    float uu = b2f(ub[row * DINNER + d]);
    float bco = dl * uu;
    const f32x4* Bp = (const f32x4*)&bcv[row * 32];
#pragma unroll
    for (int sv = 0; sv < 4; ++sv) {
      f32x4 Bv = Bp[sv];
#pragma unroll
      for (int j = 0; j < 4; ++j) {
        int s = sv * 4 + j;
        float dA = __expf(dl * Av[s]);
        P[s] *= dA;
        Q[s] = dA * Q[s] + bco * Bv[j];
      }
    }
  }
  size_t base = (((size_t)b * NC + c) * DINNER + d) * 16;
#pragma unroll
  for (int sv = 0; sv < 4; ++sv) {
    f32x4 pv, qv;
#pragma unroll
    for (int j = 0; j < 4; ++j) { pv[j] = P[sv * 4 + j]; qv[j] = Q[sv * 4 + j]; }
    *(f32x4*)&Pc[base + sv * 4] = pv;
    *(f32x4*)&Qc[base + sv * 4] = qv;
  }
}

__global__ __launch_bounds__(256) void k_scan_p2(
    const float* __restrict__ Pc, const float* __restrict__ Qc,
    float* __restrict__ Hs) {
  size_t gid = (size_t)blockIdx.x * 256 + threadIdx.x;
  size_t bds = gid & ((size_t)DINNER * 16 - 1);
  int b = (int)(gid >> 15);
  float h = 0.f;
  size_t cstride = (size_t)DINNER * 16;
  size_t base = (size_t)b * NC * cstride + bds;
  for (int c = 0; c < NC; ++c) {
    size_t idx = base + (size_t)c * cstride;
    Hs[idx] = h;
    h = Pc[idx] * h + Qc[idx];
  }
}

__global__ __launch_bounds__(256) void k_scan_p3(
    const float* __restrict__ dlt, const u16* __restrict__ ub,
    const float* __restrict__ bcv, const u16* __restrict__ xz,
    const float* __restrict__ A_log, const float* __restrict__ Dskip,
    const float* __restrict__ Hs, u16* __restrict__ yg) {
  int d = blockIdx.x * 256 + threadIdx.x;
  int c = blockIdx.y;
  int b = blockIdx.z;
  float Av[16];
#pragma unroll
  for (int sv = 0; sv < 4; ++sv) {
    f32x4 al = *(const f32x4*)&A_log[d * 16 + sv * 4];
#pragma unroll
    for (int j = 0; j < 4; ++j) Av[sv * 4 + j] = -__expf(al[j]);
  }
  float h[16];
  size_t hb = (((size_t)b * NC + c) * DINNER + d) * 16;
#pragma unroll
  for (int sv = 0; sv < 4; ++sv) {
    f32x4 hv = *(const f32x4*)&Hs[hb + sv * 4];
#pragma unroll
    for (int j = 0; j < 4; ++j) h[sv * 4 + j] = hv[j];
  }
  float Dsk = Dskip[d];
  size_t row0 = (size_t)b * SEQL + (size_t)c * TC;
  for (int t = 0; t < TC; ++t) {
    size_t row = row0 + t;
    float dl = dlt[row * DINNER + d];
    float uu = b2f(ub[row * DINNER + d]);
    float bco = dl * uu;
    const f32x4* BCp = (const f32x4*)&bcv[row * 32];
    float y = 0.f;
#pragma unroll
    for (int sv = 0; sv < 4; ++sv) {
      f32x4 Bv = BCp[sv];
      f32x4 Cv = BCp[4 + sv];
#pragma unroll
      for (int j = 0; j < 4; ++j) {
        int s = sv * 4 + j;
        float dA = __expf(dl * Av[s]);
        h[s] = dA * h[s] + bco * Bv[j];
        y += h[s] * Cv[j];
      }
    }
    float zv = b2f(xz[row * 4096 + DINNER + d]);
    float yv = (y + Dsk * uu) * (zv / (1.f + __expf(-zv)));
    yg[row * DINNER + d] = f2b(yv);
  }
}

extern "C" void kernel_launch(void* const* d_in, const int* in_sizes, int n_in,
                              void* d_out, int out_size, void* d_ws, size_t ws_size,
                              hipStream_t stream) {
  (void)in_sizes; (void)n_in; (void)out_size; (void)ws_size;
  const float* x      = (const float*)d_in[0];
  const float* ln_w   = (const float*)d_in[1];
  const float* ln_b   = (const float*)d_in[2];
  const float* W_in   = (const float*)d_in[3];
  const float* conv_w = (const float*)d_in[4];
  const float* conv_b = (const float*)d_in[5];
  const float* W_x    = (const float*)d_in[6];
  const float* W_dt   = (const float*)d_in[7];
  const float* b_dt   = (const float*)d_in[8];
  const float* A_log  = (const float*)d_in[9];
  const float* Dskip  = (const float*)d_in[10];
  const float* W_out  = (const float*)d_in[11];
  float* out = (float*)d_out;

  char* ws = (char*)d_ws;
  const size_t MB = 1048576;
  u16*  xt    = (u16*)(ws + 0 * MB);     //  8 MB bf16 (B,L,DMODEL); dead after LN
  u16*  xn    = (u16*)(ws + 8 * MB);     //  8 MB bf16; dead after gemm<0>
  u16*  WinT  = (u16*)(ws + 16 * MB);    //  8 MB bf16 (4096,1024)
  u16*  WxT   = (u16*)(ws + 24 * MB);    //  8 MB bf16 (2048,2048)
  u16*  WdtT  = (u16*)(ws + 32 * MB);    //  8 MB bf16 (2048,2048)
  u16*  WoutT = (u16*)(ws + 40 * MB);    //  4 MB bf16 (1024,2048)
  u16*  xz    = (u16*)(ws + 44 * MB);    // 32 MB bf16 (B*L, 4096)
  u16*  xbt   = (u16*)(ws + 76 * MB);    // 16 MB bf16 (B*L, DINNER)
  float* bc   = (float*)(ws + 92 * MB);  // 0.5 MB f32 (B*L, 32)
  u16*  dtin  = (u16*)(ws + 93 * MB);    // 16 MB bf16
  float* dlt  = (float*)(ws + 109 * MB); // 32 MB f32 (B*L, DINNER)
  float* Pc   = (float*)(ws + 141 * MB); //  8 MB
  float* Qc   = (float*)(ws + 149 * MB); //  8 MB
  float* Hs   = (float*)(ws + 157 * MB); //  8 MB
  float* bcp  = (float*)(ws + 165 * MB); //  8 MB split-K partials
  u16*  WxBCT = (u16*)(ws + 173 * MB);   // 128 KB bf16 (32,2048)
  u16*  yg    = (u16*)(ws + 0 * MB);     // 16 MB bf16, aliases xt+xn (dead)

  dim3 tb(32, 8);
  for (int b = 0; b < 2; ++b)
    k_transpose_cvt<<<dim3(SEQL / 32, DMODEL / 32), tb, 0, stream>>>(
        x + (size_t)b * DMODEL * SEQL, xt + (size_t)b * SEQL * DMODEL, DMODEL, SEQL, 0);
  k_transpose_cvt<<<dim3(4096 / 32, 1024 / 32), tb, 0, stream>>>(W_in, WinT, 1024, 4096, 0);
  k_transpose_cvt<<<dim3(2048 / 32, 2048 / 32), tb, 0, stream>>>(W_x, WxT, 2048, 2080, 32);
  k_transpose_cvt<<<dim3(1, 2048 / 32), tb, 0, stream>>>(W_x, WxBCT, 2048, 2080, 0);
  k_transpose_cvt<<<dim3(2048 / 32, 2048 / 32), tb, 0, stream>>>(W_dt, WdtT, 2048, 2048, 0);
  k_transpose_cvt<<<dim3(1024 / 32, 2048 / 32), tb, 0, stream>>>(W_out, WoutT, 2048, 1024, 0);

  k_layernorm<<<4096, 256, 0, stream>>>(xt, ln_w, ln_b, xn);

  // xz = xn @ W_in   (4096 x 4096, K=1024), bf16 out -- 1024 blocks
  gemm8p<1><<<1024, 256, 0, stream>>>(xn, WinT, xz, nullptr, nullptr, 4096, 4096, 1024);

  k_conv_silu<<<32768, 256, 0, stream>>>(xz, conv_w, conv_b, xbt);

  // bc = xbt @ W_x[:, :32]
  k_bc_mfma<<<dim3(4096 / 128, KS), 256, 0, stream>>>(xbt, WxBCT, bcp);
  k_bc_red<<<131072 / 256, 256, 0, stream>>>(bcp, bc);

  // dtin = xbt @ W_x[:,32:]  (bf16 out) -- 512 blocks
  gemm8p<1><<<512, 256, 0, stream>>>(xbt, WxT, dtin, nullptr, nullptr, 4096, 2048, 2048);

  // dlt = softplus(dtin @ W_dt + b_dt)  (f32 out) -- 512 blocks
  gemm8p<2><<<512, 256, 0, stream>>>(dtin, WdtT, dlt, b_dt, nullptr, 4096, 2048, 2048);

  // chunked scan
  k_scan_p1<<<dim3(DINNER / 256, NC, 2), 256, 0, stream>>>(dlt, xbt, bc, A_log, Pc, Qc);
  k_scan_p2<<<256, 256, 0, stream>>>(Pc, Qc, Hs);
  k_scan_p3<<<dim3(DINNER / 256, NC, 2), 256, 0, stream>>>(
      dlt, xbt, bc, xz, A_log, Dskip, Hs, yg);

  // out = yg @ W_out, transposed store + residual -- 256 blocks
  gemm8p<3><<<256, 256, 0, stream>>>(yg, WoutT, out, nullptr, x, 4096, 1024, 2048);
}

// Round 8
// 310.896 us; speedup vs baseline: 1.3220x; 1.0775x over previous
//
#include <hip/hip_runtime.h>
#include <cstdint>
#include <cstddef>

#define SEQL 2048
#define DMODEL 1024
#define DINNER 2048
#define NSTATE 16
#define NC 32          // scan chunks
#define TC 64          // SEQL / NC
#define KS 16          // k_bc split-K chunks
#define KCH 128        // DINNER / KS

typedef __attribute__((ext_vector_type(4))) float f32x4;
typedef __attribute__((ext_vector_type(8))) short short8;
typedef __attribute__((ext_vector_type(4))) short short4v;
typedef unsigned short u16;

__device__ __forceinline__ float b2f(u16 u) {
  union { unsigned int i; float f; } v; v.i = ((unsigned int)u) << 16; return v.f;
}
__device__ __forceinline__ u16 f2b(float f) {
  union { float f; unsigned int i; } v; v.f = f;
  unsigned int r = v.i + 0x7FFFu + ((v.i >> 16) & 1u);
  return (u16)(r >> 16);
}

// ---- transpose + fp32->bf16 : out[c][r] = in[r][c0+c], out is (Cout x R)
__global__ __launch_bounds__(256) void k_transpose_cvt(
    const float* __restrict__ in, u16* __restrict__ out, int R, int C, int c0) {
  __shared__ float t[32][33];
  int cb = blockIdx.x * 32, rb = blockIdx.y * 32;
  int tx = threadIdx.x, ty = threadIdx.y;
#pragma unroll
  for (int i = 0; i < 32; i += 8)
    t[ty + i][tx] = in[(size_t)(rb + ty + i) * C + c0 + cb + tx];
  __syncthreads();
#pragma unroll
  for (int i = 0; i < 32; i += 8)
    out[(size_t)(cb + ty + i) * R + rb + tx] = f2b(t[tx][ty + i]);
}

// ---- straight row-convert: WxRaw[r][c] = bf16(W_x[r][32+c]), 2048x2048
__global__ __launch_bounds__(256) void k_cvt_rows(
    const float* __restrict__ in, u16* __restrict__ out) {
  size_t idx = (size_t)blockIdx.x * 256 + threadIdx.x;  // elems/4
  size_t i4 = idx * 4;
  int r = (int)(i4 >> 11), c = (int)(i4 & 2047);
  f32x4 v = *(const f32x4*)&in[(size_t)r * 2080 + 32 + c];
  short4v o;
#pragma unroll
  for (int j = 0; j < 4; ++j) o[j] = (short)f2b(v[j]);
  *(short4v*)&out[i4] = o;
}

// ---- LayerNorm over DMODEL, rows = B*L, bf16 in -> bf16 out
__global__ __launch_bounds__(256) void k_layernorm(
    const u16* __restrict__ xt, const float* __restrict__ w,
    const float* __restrict__ b, u16* __restrict__ xn) {
  int row = blockIdx.x;
  const u16* px = xt + (size_t)row * DMODEL;
  int i4 = threadIdx.x * 4;
  short4v sv = *(const short4v*)&px[i4];
  float v[4];
#pragma unroll
  for (int j = 0; j < 4; ++j) v[j] = b2f((u16)sv[j]);
  float s1 = v[0] + v[1] + v[2] + v[3];
  float s2 = v[0]*v[0] + v[1]*v[1] + v[2]*v[2] + v[3]*v[3];
#pragma unroll
  for (int off = 32; off > 0; off >>= 1) {
    s1 += __shfl_xor(s1, off);
    s2 += __shfl_xor(s2, off);
  }
  __shared__ float a1[4], a2[4];
  int lane = threadIdx.x & 63, wid = threadIdx.x >> 6;
  if (lane == 0) { a1[wid] = s1; a2[wid] = s2; }
  __syncthreads();
  float t1 = a1[0] + a1[1] + a1[2] + a1[3];
  float t2 = a2[0] + a2[1] + a2[2] + a2[3];
  float mu = t1 * (1.f / DMODEL);
  float rs = rsqrtf(t2 * (1.f / DMODEL) - mu * mu + 1e-5f);
  short4v ov;
#pragma unroll
  for (int j = 0; j < 4; ++j) ov[j] = (short)f2b((v[j] - mu) * rs * w[i4 + j] + b[i4 + j]);
  *(short4v*)&xn[(size_t)row * DMODEL + i4] = ov;
}

// ==================== 4-phase 128x128 MFMA GEMM, 2 blocks/CU ====================
// C[M,N] = A[M,K] * BT[N,K]^T. 256 threads = 4 waves (2 M x 2 N), BK=64,
// double-buffered swizzled LDS, counted vmcnt, setprio, XCD swizzle.
// All staging/frag addresses hoisted to registers; main loop unrolled x2 so
// buffer parity and stage offsets are compile-time.
// EPI: 0 f32; 1 bf16; 2 f32 softplus(acc+bias[col]); 3 transposed + residual.
template<int EPI>
__global__ __launch_bounds__(256) void gemm8p(
    const u16* __restrict__ A, const u16* __restrict__ BT,
    void* __restrict__ outp, const float* __restrict__ bias,
    const float* __restrict__ resid, int M, int N, int K) {
  constexpr int LDSTILE = 2 * 128 * 64;   // elems per buffer (A + B)
  __shared__ u16 lds[2 * LDSTILE];        // 64 KiB

  const int tid = threadIdx.x;
  const int w = tid >> 6, lane = tid & 63;
  const int wm = w >> 1, wn = w & 1;
  const int lg = lane >> 4, lr = lane & 15;
  const int wbase = tid & ~63;

  const int gx = N / 128;
  const int cpx = gridDim.x >> 3;
  const int wg = ((int)blockIdx.x & 7) * cpx + ((int)blockIdx.x >> 3);
  const int tm = (wg / gx) * 128;
  const int tn = (wg % gx) * 128;
  const int NT = K >> 6;

  // ---- hoisted staging addresses (h=0 base; h adds 32*K src / 2048 dst)
  const u16* aSp[2];
  const u16* bSp[2];
  int aD[2], bD[2];
#pragma unroll
  for (int j = 0; j < 2; ++j) {
    int t8 = j * 256 + tid;
    int r8 = t8 >> 3;
    int pr = (r8 & 31) + ((r8 >> 5) << 6);
    int sk = ((((t8 & 7) << 4) ^ ((pr & 7) << 4)) >> 1);
    aSp[j] = A + (size_t)(tm + pr) * K + sk;
    bSp[j] = BT + (size_t)(tn + pr) * K + sk;
    int r8b = (j * 256 + wbase) >> 3;
    int prb = (r8b & 31) + ((r8b >> 5) << 6);
    aD[j] = prb * 64;
    bD[j] = 128 * 64 + prb * 64;
  }
  // ---- hoisted fragment LDS byte offsets
  int aFo[4][2], bFo[4][2];
#pragma unroll
  for (int mf = 0; mf < 4; ++mf)
#pragma unroll
    for (int kk = 0; kk < 2; ++kk) {
      int r = wm * 64 + mf * 16 + lr;
      aFo[mf][kk] = r * 128 + ((kk * 64 + lg * 16) ^ ((r & 7) << 4));
      int rb = wn * 64 + mf * 16 + lr;
      bFo[mf][kk] = 128 * 64 * 2 + rb * 128 + ((kk * 64 + lg * 16) ^ ((rb & 7) << 4));
    }

  auto stA = [&](int toff, int h, int buf) {
#pragma unroll
    for (int j = 0; j < 2; ++j)
      __builtin_amdgcn_global_load_lds(
          (const __attribute__((address_space(1))) void*)(aSp[j] + toff * 64 + h * (K << 5)),
          (__attribute__((address_space(3))) void*)(lds + buf * LDSTILE + aD[j] + h * 2048),
          16, 0, 0);
  };
  auto stB = [&](int toff, int h, int buf) {
#pragma unroll
    for (int j = 0; j < 2; ++j)
      __builtin_amdgcn_global_load_lds(
          (const __attribute__((address_space(1))) void*)(bSp[j] + toff * 64 + h * (K << 5)),
          (__attribute__((address_space(3))) void*)(lds + buf * LDSTILE + bD[j] + h * 2048),
          16, 0, 0);
  };

  f32x4 acc[4][4] = {};
  short8 aF[2][2], bF0[2][2], bF1[2][2];

  // prologue: tile0 fully + first halves of tile1 (6 stage-pairs = 12 loads)
  stA(0, 0, 0); stB(0, 0, 0); stB(0, 1, 0); stA(0, 1, 0);
  stA(1, 0, 1); stB(1, 0, 1);
  asm volatile("s_waitcnt vmcnt(4)" ::: "memory");
  __builtin_amdgcn_s_barrier();

  for (int tt = 0; tt < NT; tt += 2) {
#pragma unroll
    for (int u = 0; u < 2; ++u) {
      const char* Lb = (const char*)lds + u * (LDSTILE * 2);
      // ---- P1: read A-h0 + B-h0; stage B-h1(t+1); MFMA Q(01,01)
#pragma unroll
      for (int mf = 0; mf < 2; ++mf)
#pragma unroll
        for (int kk = 0; kk < 2; ++kk) aF[mf][kk] = *(const short8*)(Lb + aFo[mf][kk]);
#pragma unroll
      for (int nf = 0; nf < 2; ++nf)
#pragma unroll
        for (int kk = 0; kk < 2; ++kk) bF0[nf][kk] = *(const short8*)(Lb + bFo[nf][kk]);
      stB(u + 1, 1, (u + 1) & 1);
      __builtin_amdgcn_s_barrier();
      asm volatile("s_waitcnt lgkmcnt(0)" ::: "memory");
      __builtin_amdgcn_s_setprio(1);
#pragma unroll
      for (int mf = 0; mf < 2; ++mf)
#pragma unroll
        for (int nf = 0; nf < 2; ++nf) {
          acc[mf][nf] = __builtin_amdgcn_mfma_f32_16x16x32_bf16(aF[mf][0], bF0[nf][0], acc[mf][nf], 0, 0, 0);
          acc[mf][nf] = __builtin_amdgcn_mfma_f32_16x16x32_bf16(aF[mf][1], bF0[nf][1], acc[mf][nf], 0, 0, 0);
        }
      __builtin_amdgcn_s_setprio(0);
      __builtin_amdgcn_s_barrier();
      // ---- P2: read B-h1; stage A-h1(t+1); MFMA Q(01,23)
#pragma unroll
      for (int nf = 0; nf < 2; ++nf)
#pragma unroll
        for (int kk = 0; kk < 2; ++kk) bF1[nf][kk] = *(const short8*)(Lb + bFo[2 + nf][kk]);
      stA(u + 1, 1, (u + 1) & 1);
      __builtin_amdgcn_s_barrier();
      asm volatile("s_waitcnt lgkmcnt(0)" ::: "memory");
      __builtin_amdgcn_s_setprio(1);
#pragma unroll
      for (int mf = 0; mf < 2; ++mf)
#pragma unroll
        for (int nf = 0; nf < 2; ++nf) {
          acc[mf][2 + nf] = __builtin_amdgcn_mfma_f32_16x16x32_bf16(aF[mf][0], bF1[nf][0], acc[mf][2 + nf], 0, 0, 0);
          acc[mf][2 + nf] = __builtin_amdgcn_mfma_f32_16x16x32_bf16(aF[mf][1], bF1[nf][1], acc[mf][2 + nf], 0, 0, 0);
        }
      __builtin_amdgcn_s_setprio(0);
      __builtin_amdgcn_s_barrier();
      // ---- P3: read A-h1; stage A-h0(t+2); MFMA Q(23,01)
#pragma unroll
      for (int mf = 0; mf < 2; ++mf)
#pragma unroll
        for (int kk = 0; kk < 2; ++kk) aF[mf][kk] = *(const short8*)(Lb + aFo[2 + mf][kk]);
      stA(u + 2, 0, u & 1);
      __builtin_amdgcn_s_barrier();
      asm volatile("s_waitcnt lgkmcnt(0)" ::: "memory");
      __builtin_amdgcn_s_setprio(1);
#pragma unroll
      for (int mf = 0; mf < 2; ++mf)
#pragma unroll
        for (int nf = 0; nf < 2; ++nf) {
          acc[2 + mf][nf] = __builtin_amdgcn_mfma_f32_16x16x32_bf16(aF[mf][0], bF0[nf][0], acc[2 + mf][nf], 0, 0, 0);
          acc[2 + mf][nf] = __builtin_amdgcn_mfma_f32_16x16x32_bf16(aF[mf][1], bF0[nf][1], acc[2 + mf][nf], 0, 0, 0);
        }
      __builtin_amdgcn_s_setprio(0);
      __builtin_amdgcn_s_barrier();
      // ---- P4: MFMA Q(23,23); stage B-h0(t+2); counted vmcnt
      stB(u + 2, 0, u & 1);
      __builtin_amdgcn_s_barrier();
      asm volatile("s_waitcnt lgkmcnt(0)" ::: "memory");
      __builtin_amdgcn_s_setprio(1);
#pragma unroll
      for (int mf = 0; mf < 2; ++mf)
#pragma unroll
        for (int nf = 0; nf < 2; ++nf) {
          acc[2 + mf][2 + nf] = __builtin_amdgcn_mfma_f32_16x16x32_bf16(aF[mf][0], bF1[nf][0], acc[2 + mf][2 + nf], 0, 0, 0);
          acc[2 + mf][2 + nf] = __builtin_amdgcn_mfma_f32_16x16x32_bf16(aF[mf][1], bF1[nf][1], acc[2 + mf][2 + nf], 0, 0, 0);
        }
      __builtin_amdgcn_s_setprio(0);
      asm volatile("s_waitcnt vmcnt(4)" ::: "memory");
      __builtin_amdgcn_s_barrier();
    }
#pragma unroll
    for (int j = 0; j < 2; ++j) { aSp[j] += 128; bSp[j] += 128; }
  }

  // epilogue
#pragma unroll
  for (int mf = 0; mf < 4; ++mf) {
    int r0 = tm + wm * 64 + mf * 16 + lg * 4;
#pragma unroll
    for (int nf = 0; nf < 4; ++nf) {
      int c = tn + wn * 64 + nf * 16 + lr;
      f32x4 v = acc[mf][nf];
#pragma unroll
      for (int j = 0; j < 4; ++j) {
        int r = r0 + j;
        if constexpr (EPI == 1) {
          ((u16*)outp)[(size_t)r * N + c] = f2b(v[j]);
        } else if constexpr (EPI == 2) {
          float xv = v[j] + bias[c];
          ((float*)outp)[(size_t)r * N + c] = (xv > 20.f) ? xv : log1pf(__expf(xv));
        } else if constexpr (EPI == 3) {
          int bb = r >> 11, tt2 = r & (SEQL - 1);
          size_t oi = ((size_t)(bb * N + c)) * SEQL + tt2;
          ((float*)outp)[oi] = v[j] + resid[oi];
        } else {
          ((float*)outp)[(size_t)r * N + c] = v[j];
        }
      }
    }
  }
}

// ---- depthwise causal conv(k=4) + bias + silu; 2 d-lanes per thread
__global__ __launch_bounds__(256) void k_conv_silu(
    const u16* __restrict__ xz, const float* __restrict__ cw,
    const float* __restrict__ cb, u16* __restrict__ xbt) {
  size_t idx = (size_t)blockIdx.x * 256 + threadIdx.x;  // B*L*DINNER/2
  int d2 = (int)(idx & (DINNER / 2 - 1));
  int d = d2 * 2;
  int l = (int)((idx >> 10) & (SEQL - 1));
  int b = (int)(idx >> 21);
  f32x4 w0 = *(const f32x4*)&cw[d * 4];
  f32x4 w1 = *(const f32x4*)&cw[d * 4 + 4];
  float a0 = cb[d], a1 = cb[d + 1];
  size_t base = ((size_t)b * SEQL + l) * 4096 + d;
#pragma unroll
  for (int i = 0; i < 4; ++i) {
    int ls = l - 3 + i;
    if (ls >= 0) {
      unsigned int pv = *(const unsigned int*)&xz[base + (size_t)(i - 3) * 4096];
      a0 += w0[i] * b2f((u16)(pv & 0xFFFF));
      a1 += w1[i] * b2f((u16)(pv >> 16));
    }
  }
  float s0 = a0 / (1.f + __expf(-a0));
  float s1 = a1 / (1.f + __expf(-a1));
  unsigned int ov = (unsigned int)f2b(s0) | ((unsigned int)f2b(s1) << 16);
  *(unsigned int*)&xbt[((size_t)b * SEQL + l) * DINNER + d] = ov;
}

// ---- split-K MFMA skinny GEMM: bcp[ks][r][j] = sum_{k in chunk} xbt[r,k]*WxBCT[j,k]
__global__ __launch_bounds__(256) void k_bc_mfma(
    const u16* __restrict__ xbt, const u16* __restrict__ WxBCT,
    float* __restrict__ bcp) {
  __shared__ u16 As[128 * 32];
  int tid = threadIdx.x;
  int w = tid >> 6, lane = tid & 63;
  int tm = blockIdx.x * 128;
  int k0 = blockIdx.y * KCH;
  int lg = lane >> 4, lr = lane & 15;
  int srow = lane >> 2, scol = (lane & 3) * 8;

  f32x4 acc[2][2] = {};

  for (int kk = k0; kk < k0 + KCH; kk += 32) {
#pragma unroll
    for (int j = 0; j < 2; ++j) {
      int ch = w * 2 + j;
      const u16* ga = xbt + (size_t)(tm + ch * 16 + srow) * DINNER + kk + scol;
      __builtin_amdgcn_global_load_lds(
          (const __attribute__((address_space(1))) void*)ga,
          (__attribute__((address_space(3))) void*)&As[ch * 512], 16, 0, 0);
    }
    __syncthreads();
    short8 aF[2], bF[2];
#pragma unroll
    for (int m = 0; m < 2; ++m)
      aF[m] = *(const short8*)&As[(w * 32 + m * 16 + lr) * 32 + lg * 8];
#pragma unroll
    for (int n = 0; n < 2; ++n)
      bF[n] = *(const short8*)&WxBCT[(size_t)(n * 16 + lr) * DINNER + kk + lg * 8];
#pragma unroll
    for (int m = 0; m < 2; ++m)
#pragma unroll
      for (int n = 0; n < 2; ++n)
        acc[m][n] = __builtin_amdgcn_mfma_f32_16x16x32_bf16(aF[m], bF[n], acc[m][n], 0, 0, 0);
    __syncthreads();
  }

  float* outp = bcp + (size_t)blockIdx.y * (4096 * 32);
#pragma unroll
  for (int m = 0; m < 2; ++m) {
    int r0 = tm + w * 32 + m * 16 + lg * 4;
#pragma unroll
    for (int n = 0; n < 2; ++n) {
      int c = n * 16 + lr;
      f32x4 v = acc[m][n];
#pragma unroll
      for (int j = 0; j < 4; ++j)
        outp[(size_t)(r0 + j) * 32 + c] = v[j];
    }
  }
}

// ---- reduce split-K partials
__global__ __launch_bounds__(256) void k_bc_red(
    const float* __restrict__ bcp, float* __restrict__ bc) {
  size_t i = (size_t)blockIdx.x * 256 + threadIdx.x;
  float s = 0.f;
#pragma unroll
  for (int ks = 0; ks < KS; ++ks)
    s += bcp[(size_t)ks * (4096 * 32) + i];
  bc[i] = s;
}

// ==== chunked selective scan ====
__global__ __launch_bounds__(256) void k_scan_p1(
    const float* __restrict__ dlt, const u16* __restrict__ ub,
    const float* __restrict__ bcv, const float* __restrict__ A_log,
    float* __restrict__ Pc, float* __restrict__ Qc) {
  int d = blockIdx.x * 256 + threadIdx.x;
  int c = blockIdx.y;
  int b = blockIdx.z;
  float Av[16];
#pragma unroll
  for (int sv = 0; sv < 4; ++sv) {
    f32x4 al = *(const f32x4*)&A_log[d * 16 + sv * 4];
#pragma unroll
    for (int j = 0; j < 4; ++j) Av[sv * 4 + j] = -__expf(al[j]);
  }
  float P[16], Q[16];
#pragma unroll
  for (int s = 0; s < 16; ++s) { P[s] = 1.f; Q[s] = 0.f; }
  size_t row0 = (size_t)b * SEQL + (size_t)c * TC;
  for (int t = 0; t < TC; ++t) {
    size_t row = row0 + t;
    float dl = dlt[row * DINNER + d];
    float uu = b2f(ub[row * DINNER + d]);
    float bco = dl * uu;
    const f32x4* Bp = (const f32x4*)&bcv[row * 32];
#pragma unroll
    for (int sv = 0; sv < 4; ++sv) {
      f32x4 Bv = Bp[sv];
#pragma unroll
      for (int j = 0; j < 4; ++j) {
        int s = sv * 4 + j;
        float dA = __expf(dl * Av[s]);
        P[s] *= dA;
        Q[s] = dA * Q[s] + bco * Bv[j];
      }
    }
  }
  size_t base = (((size_t)b * NC + c) * DINNER + d) * 16;
#pragma unroll
  for (int sv = 0; sv < 4; ++sv) {
    f32x4 pv, qv;
#pragma unroll
    for (int j = 0; j < 4; ++j) { pv[j] = P[sv * 4 + j]; qv[j] = Q[sv * 4 + j]; }
    *(f32x4*)&Pc[base + sv * 4] = pv;
    *(f32x4*)&Qc[base + sv * 4] = qv;
  }
}

__global__ __launch_bounds__(256) void k_scan_p2(
    const float* __restrict__ Pc, const float* __restrict__ Qc,
    float* __restrict__ Hs) {
  size_t gid = (size_t)blockIdx.x * 256 + threadIdx.x;
  size_t bds = gid & ((size_t)DINNER * 16 - 1);
  int b = (int)(gid >> 15);
  float h = 0.f;
  size_t cstride = (size_t)DINNER * 16;
  size_t base = (size_t)b * NC * cstride + bds;
  for (int c = 0; c < NC; ++c) {
    size_t idx = base + (size_t)c * cstride;
    Hs[idx] = h;
    h = Pc[idx] * h + Qc[idx];
  }
}

__global__ __launch_bounds__(256) void k_scan_p3(
    const float* __restrict__ dlt, const u16* __restrict__ ub,
    const float* __restrict__ bcv, const u16* __restrict__ xz,
    const float* __restrict__ A_log, const float* __restrict__ Dskip,
    const float* __restrict__ Hs, u16* __restrict__ yg) {
  int d = blockIdx.x * 256 + threadIdx.x;
  int c = blockIdx.y;
  int b = blockIdx.z;
  float Av[16];
#pragma unroll
  for (int sv = 0; sv < 4; ++sv) {
    f32x4 al = *(const f32x4*)&A_log[d * 16 + sv * 4];
#pragma unroll
    for (int j = 0; j < 4; ++j) Av[sv * 4 + j] = -__expf(al[j]);
  }
  float h[16];
  size_t hb = (((size_t)b * NC + c) * DINNER + d) * 16;
#pragma unroll
  for (int sv = 0; sv < 4; ++sv) {
    f32x4 hv = *(const f32x4*)&Hs[hb + sv * 4];
#pragma unroll
    for (int j = 0; j < 4; ++j) h[sv * 4 + j] = hv[j];
  }
  float Dsk = Dskip[d];
  size_t row0 = (size_t)b * SEQL + (size_t)c * TC;
  for (int t = 0; t < TC; ++t) {
    size_t row = row0 + t;
    float dl = dlt[row * DINNER + d];
    float uu = b2f(ub[row * DINNER + d]);
    float bco = dl * uu;
    const f32x4* BCp = (const f32x4*)&bcv[row * 32];
    float y = 0.f;
#pragma unroll
    for (int sv = 0; sv < 4; ++sv) {
      f32x4 Bv = BCp[sv];
      f32x4 Cv = BCp[4 + sv];
#pragma unroll
      for (int j = 0; j < 4; ++j) {
        int s = sv * 4 + j;
        float dA = __expf(dl * Av[s]);
        h[s] = dA * h[s] + bco * Bv[j];
        y += h[s] * Cv[j];
      }
    }
    float zv = b2f(xz[row * 4096 + DINNER + d]);
    float yv = (y + Dsk * uu) * (zv / (1.f + __expf(-zv)));
    yg[row * DINNER + d] = f2b(yv);
  }
}

extern "C" void kernel_launch(void* const* d_in, const int* in_sizes, int n_in,
                              void* d_out, int out_size, void* d_ws, size_t ws_size,
                              hipStream_t stream) {
  (void)in_sizes; (void)n_in; (void)out_size; (void)ws_size;
  const float* x      = (const float*)d_in[0];
  const float* ln_w   = (const float*)d_in[1];
  const float* ln_b   = (const float*)d_in[2];
  const float* W_in   = (const float*)d_in[3];
  const float* conv_w = (const float*)d_in[4];
  const float* conv_b = (const float*)d_in[5];
  const float* W_x    = (const float*)d_in[6];
  const float* W_dt   = (const float*)d_in[7];
  const float* b_dt   = (const float*)d_in[8];
  const float* A_log  = (const float*)d_in[9];
  const float* Dskip  = (const float*)d_in[10];
  const float* W_out  = (const float*)d_in[11];
  float* out = (float*)d_out;

  char* ws = (char*)d_ws;
  const size_t MB = 1048576;
  u16*  xt    = (u16*)(ws + 0 * MB);     //  8 MB bf16; dead after LN
  u16*  xn    = (u16*)(ws + 8 * MB);     //  8 MB bf16; dead after xz gemm
  u16*  WinT  = (u16*)(ws + 16 * MB);    //  8 MB bf16 (4096,1024)
  u16*  WdtT  = (u16*)(ws + 32 * MB);    //  8 MB bf16 (2048,2048)
  u16*  WoutT = (u16*)(ws + 40 * MB);    //  4 MB bf16 (1024,2048)
  u16*  xz    = (u16*)(ws + 44 * MB);    // 32 MB bf16 (B*L, 4096)
  u16*  xbt   = (u16*)(ws + 76 * MB);    // 16 MB bf16 (B*L, DINNER)
  float* bc   = (float*)(ws + 92 * MB);  // 0.5 MB f32 (B*L, 32)
  u16*  WxRaw = (u16*)(ws + 93 * MB);    //  8 MB bf16 W_x[:,32:] row-major
  u16*  W_cT  = (u16*)(ws + 101 * MB);   //  8 MB bf16 combined weight (N,K)
  float* dlt  = (float*)(ws + 109 * MB); // 32 MB f32 (B*L, DINNER)
  float* Pc   = (float*)(ws + 141 * MB); //  8 MB
  float* Qc   = (float*)(ws + 149 * MB); //  8 MB
  float* Hs   = (float*)(ws + 157 * MB); //  8 MB
  float* bcp  = (float*)(ws + 165 * MB); //  8 MB split-K partials
  u16*  WxBCT = (u16*)(ws + 173 * MB);   // 128 KB bf16 (32,2048)
  u16*  yg    = (u16*)(ws + 0 * MB);     // 16 MB bf16, aliases xt+xn (dead)

  dim3 tb(32, 8);
  for (int b = 0; b < 2; ++b)
    k_transpose_cvt<<<dim3(SEQL / 32, DMODEL / 32), tb, 0, stream>>>(
        x + (size_t)b * DMODEL * SEQL, xt + (size_t)b * SEQL * DMODEL, DMODEL, SEQL, 0);
  k_transpose_cvt<<<dim3(4096 / 32, 1024 / 32), tb, 0, stream>>>(W_in, WinT, 1024, 4096, 0);
  k_transpose_cvt<<<dim3(1, 2048 / 32), tb, 0, stream>>>(W_x, WxBCT, 2048, 2080, 0);
  k_transpose_cvt<<<dim3(2048 / 32, 2048 / 32), tb, 0, stream>>>(W_dt, WdtT, 2048, 2048, 0);
  k_transpose_cvt<<<dim3(1024 / 32, 2048 / 32), tb, 0, stream>>>(W_out, WoutT, 2048, 1024, 0);
  k_cvt_rows<<<4096, 256, 0, stream>>>(W_x, WxRaw);

  // W_cT[n,k] = (Wx' @ W_dt)[k,n] : A=WdtT, BT=WxRaw, 2048^3
  gemm8p<1><<<256, 256, 0, stream>>>(WdtT, WxRaw, W_cT, nullptr, nullptr, 2048, 2048, 2048);

  k_layernorm<<<4096, 256, 0, stream>>>(xt, ln_w, ln_b, xn);

  // xz = xn @ W_in   (4096 x 4096, K=1024), bf16 out
  gemm8p<1><<<1024, 256, 0, stream>>>(xn, WinT, xz, nullptr, nullptr, 4096, 4096, 1024);

  k_conv_silu<<<16384, 256, 0, stream>>>(xz, conv_w, conv_b, xbt);

  // bc = xbt @ W_x[:, :32]
  k_bc_mfma<<<dim3(4096 / 128, KS), 256, 0, stream>>>(xbt, WxBCT, bcp);
  k_bc_red<<<131072 / 256, 256, 0, stream>>>(bcp, bc);

  // dlt = softplus(xbt @ W_c + b_dt)  (f32 out), fused weight
  gemm8p<2><<<512, 256, 0, stream>>>(xbt, W_cT, dlt, b_dt, nullptr, 4096, 2048, 2048);

  // chunked scan
  k_scan_p1<<<dim3(DINNER / 256, NC, 2), 256, 0, stream>>>(dlt, xbt, bc, A_log, Pc, Qc);
  k_scan_p2<<<256, 256, 0, stream>>>(Pc, Qc, Hs);
  k_scan_p3<<<dim3(DINNER / 256, NC, 2), 256, 0, stream>>>(
      dlt, xbt, bc, xz, A_log, Dskip, Hs, yg);

  // out = yg @ W_out, transposed store + residual
  gemm8p<3><<<256, 256, 0, stream>>>(yg, WoutT, out, nullptr, x, 4096, 1024, 2048);
}

// Round 9
// 306.271 us; speedup vs baseline: 1.3420x; 1.0151x over previous
//
#include <hip/hip_runtime.h>
#include <cstdint>
#include <cstddef>

#define SEQL 2048
#define DMODEL 1024
#define DINNER 2048
#define NSTATE 16
#define NC 32          // scan chunks
#define TC 64          // SEQL / NC
#define KS 16          // k_bc split-K chunks
#define KCH 128        // DINNER / KS

typedef __attribute__((ext_vector_type(4))) float f32x4;
typedef __attribute__((ext_vector_type(8))) short short8;
typedef __attribute__((ext_vector_type(4))) short short4v;
typedef unsigned short u16;

__device__ __forceinline__ float b2f(u16 u) {
  union { unsigned int i; float f; } v; v.i = ((unsigned int)u) << 16; return v.f;
}
__device__ __forceinline__ u16 f2b(float f) {
  union { float f; unsigned int i; } v; v.f = f;
  unsigned int r = v.i + 0x7FFFu + ((v.i >> 16) & 1u);
  return (u16)(r >> 16);
}

// ---- transpose + fp32->bf16 : out[c][r] = in[r][c0+c], out is (Cout x R)
__global__ __launch_bounds__(256) void k_transpose_cvt(
    const float* __restrict__ in, u16* __restrict__ out, int R, int C, int c0) {
  __shared__ float t[32][33];
  int cb = blockIdx.x * 32, rb = blockIdx.y * 32;
  int tx = threadIdx.x, ty = threadIdx.y;
#pragma unroll
  for (int i = 0; i < 32; i += 8)
    t[ty + i][tx] = in[(size_t)(rb + ty + i) * C + c0 + cb + tx];
  __syncthreads();
#pragma unroll
  for (int i = 0; i < 32; i += 8)
    out[(size_t)(cb + ty + i) * R + rb + tx] = f2b(t[tx][ty + i]);
}

// ---- straight row-convert: WxRaw[r][c] = bf16(W_x[r][32+c]), 2048x2048
__global__ __launch_bounds__(256) void k_cvt_rows(
    const float* __restrict__ in, u16* __restrict__ out) {
  size_t idx = (size_t)blockIdx.x * 256 + threadIdx.x;  // elems/4
  size_t i4 = idx * 4;
  int r = (int)(i4 >> 11), c = (int)(i4 & 2047);
  f32x4 v = *(const f32x4*)&in[(size_t)r * 2080 + 32 + c];
  short4v o;
#pragma unroll
  for (int j = 0; j < 4; ++j) o[j] = (short)f2b(v[j]);
  *(short4v*)&out[i4] = o;
}

// ---- LayerNorm over DMODEL, rows = B*L, bf16 in -> bf16 out
__global__ __launch_bounds__(256) void k_layernorm(
    const u16* __restrict__ xt, const float* __restrict__ w,
    const float* __restrict__ b, u16* __restrict__ xn) {
  int row = blockIdx.x;
  const u16* px = xt + (size_t)row * DMODEL;
  int i4 = threadIdx.x * 4;
  short4v sv = *(const short4v*)&px[i4];
  float v[4];
#pragma unroll
  for (int j = 0; j < 4; ++j) v[j] = b2f((u16)sv[j]);
  float s1 = v[0] + v[1] + v[2] + v[3];
  float s2 = v[0]*v[0] + v[1]*v[1] + v[2]*v[2] + v[3]*v[3];
#pragma unroll
  for (int off = 32; off > 0; off >>= 1) {
    s1 += __shfl_xor(s1, off);
    s2 += __shfl_xor(s2, off);
  }
  __shared__ float a1[4], a2[4];
  int lane = threadIdx.x & 63, wid = threadIdx.x >> 6;
  if (lane == 0) { a1[wid] = s1; a2[wid] = s2; }
  __syncthreads();
  float t1 = a1[0] + a1[1] + a1[2] + a1[3];
  float t2 = a2[0] + a2[1] + a2[2] + a2[3];
  float mu = t1 * (1.f / DMODEL);
  float rs = rsqrtf(t2 * (1.f / DMODEL) - mu * mu + 1e-5f);
  short4v ov;
#pragma unroll
  for (int j = 0; j < 4; ++j) ov[j] = (short)f2b((v[j] - mu) * rs * w[i4 + j] + b[i4 + j]);
  *(short4v*)&xn[(size_t)row * DMODEL + i4] = ov;
}

// ==================== 4-phase 128x128 MFMA GEMM, 2 blocks/CU ====================
// C[M,N] = A[M,K] * BT[N,K]^T. 256 threads = 4 waves (2 M x 2 N), BK=64,
// double-buffered swizzled LDS, counted vmcnt, setprio.
// L2-locality: per-XCD rectangular chunk mapping (cm x cn tiles per chunk,
// sized so A+B panels fit the XCD's 4 MB L2; consecutive chunks per XCD).
// EPI: 0 f32; 1 bf16; 2 f32 softplus(acc+bias[col]); 3 transposed + residual.
template<int EPI>
__global__ __launch_bounds__(256) void gemm8p(
    const u16* __restrict__ A, const u16* __restrict__ BT,
    void* __restrict__ outp, const float* __restrict__ bias,
    const float* __restrict__ resid, int M, int N, int K, int cm, int cn) {
  constexpr int LDSTILE = 2 * 128 * 64;   // elems per buffer (A + B)
  __shared__ u16 lds[2 * LDSTILE];        // 64 KiB

  const int tid = threadIdx.x;
  const int w = tid >> 6, lane = tid & 63;
  const int wm = w >> 1, wn = w & 1;
  const int lg = lane >> 4, lr = lane & 15;
  const int wbase = tid & ~63;

  // ---- chunked XCD tile mapping
  const int gx = N / 128;
  const int csz = cm * cn;
  const int T8 = (int)gridDim.x >> 3;          // tiles per XCD
  const int xcd = (int)blockIdx.x & 7;
  const int local = (int)blockIdx.x >> 3;
  const int c = xcd * (T8 / csz) + local / csz;
  const int wi = local % csz;
  const int cgx = gx / cn;
  const int tm = ((c / cgx) * cm + wi / cn) * 128;
  const int tn = ((c % cgx) * cn + wi % cn) * 128;
  const int NT = K >> 6;

  // ---- hoisted staging addresses (h=0 base; h adds 32*K src / 2048 dst)
  const u16* aSp[2];
  const u16* bSp[2];
  int aD[2], bD[2];
#pragma unroll
  for (int j = 0; j < 2; ++j) {
    int t8 = j * 256 + tid;
    int r8 = t8 >> 3;
    int pr = (r8 & 31) + ((r8 >> 5) << 6);
    int sk = ((((t8 & 7) << 4) ^ ((pr & 7) << 4)) >> 1);
    aSp[j] = A + (size_t)(tm + pr) * K + sk;
    bSp[j] = BT + (size_t)(tn + pr) * K + sk;
    int r8b = (j * 256 + wbase) >> 3;
    int prb = (r8b & 31) + ((r8b >> 5) << 6);
    aD[j] = prb * 64;
    bD[j] = 128 * 64 + prb * 64;
  }
  // ---- hoisted fragment LDS byte offsets
  int aFo[4][2], bFo[4][2];
#pragma unroll
  for (int mf = 0; mf < 4; ++mf)
#pragma unroll
    for (int kk = 0; kk < 2; ++kk) {
      int r = wm * 64 + mf * 16 + lr;
      aFo[mf][kk] = r * 128 + ((kk * 64 + lg * 16) ^ ((r & 7) << 4));
      int rb = wn * 64 + mf * 16 + lr;
      bFo[mf][kk] = 128 * 64 * 2 + rb * 128 + ((kk * 64 + lg * 16) ^ ((rb & 7) << 4));
    }

  auto stA = [&](int toff, int h, int buf) {
#pragma unroll
    for (int j = 0; j < 2; ++j)
      __builtin_amdgcn_global_load_lds(
          (const __attribute__((address_space(1))) void*)(aSp[j] + toff * 64 + h * (K << 5)),
          (__attribute__((address_space(3))) void*)(lds + buf * LDSTILE + aD[j] + h * 2048),
          16, 0, 0);
  };
  auto stB = [&](int toff, int h, int buf) {
#pragma unroll
    for (int j = 0; j < 2; ++j)
      __builtin_amdgcn_global_load_lds(
          (const __attribute__((address_space(1))) void*)(bSp[j] + toff * 64 + h * (K << 5)),
          (__attribute__((address_space(3))) void*)(lds + buf * LDSTILE + bD[j] + h * 2048),
          16, 0, 0);
  };

  f32x4 acc[4][4] = {};
  short8 aF[2][2], bF0[2][2], bF1[2][2];

  // prologue: tile0 fully + first halves of tile1 (6 stage-pairs = 12 loads)
  stA(0, 0, 0); stB(0, 0, 0); stB(0, 1, 0); stA(0, 1, 0);
  stA(1, 0, 1); stB(1, 0, 1);
  asm volatile("s_waitcnt vmcnt(4)" ::: "memory");
  __builtin_amdgcn_s_barrier();

  for (int tt = 0; tt < NT; tt += 2) {
#pragma unroll
    for (int u = 0; u < 2; ++u) {
      const char* Lb = (const char*)lds + u * (LDSTILE * 2);
      // ---- P1: read A-h0 + B-h0; stage B-h1(t+1); MFMA Q(01,01)
#pragma unroll
      for (int mf = 0; mf < 2; ++mf)
#pragma unroll
        for (int kk = 0; kk < 2; ++kk) aF[mf][kk] = *(const short8*)(Lb + aFo[mf][kk]);
#pragma unroll
      for (int nf = 0; nf < 2; ++nf)
#pragma unroll
        for (int kk = 0; kk < 2; ++kk) bF0[nf][kk] = *(const short8*)(Lb + bFo[nf][kk]);
      stB(u + 1, 1, (u + 1) & 1);
      __builtin_amdgcn_s_barrier();
      asm volatile("s_waitcnt lgkmcnt(0)" ::: "memory");
      __builtin_amdgcn_s_setprio(1);
#pragma unroll
      for (int mf = 0; mf < 2; ++mf)
#pragma unroll
        for (int nf = 0; nf < 2; ++nf) {
          acc[mf][nf] = __builtin_amdgcn_mfma_f32_16x16x32_bf16(aF[mf][0], bF0[nf][0], acc[mf][nf], 0, 0, 0);
          acc[mf][nf] = __builtin_amdgcn_mfma_f32_16x16x32_bf16(aF[mf][1], bF0[nf][1], acc[mf][nf], 0, 0, 0);
        }
      __builtin_amdgcn_s_setprio(0);
      __builtin_amdgcn_s_barrier();
      // ---- P2: read B-h1; stage A-h1(t+1); MFMA Q(01,23)
#pragma unroll
      for (int nf = 0; nf < 2; ++nf)
#pragma unroll
        for (int kk = 0; kk < 2; ++kk) bF1[nf][kk] = *(const short8*)(Lb + bFo[2 + nf][kk]);
      stA(u + 1, 1, (u + 1) & 1);
      __builtin_amdgcn_s_barrier();
      asm volatile("s_waitcnt lgkmcnt(0)" ::: "memory");
      __builtin_amdgcn_s_setprio(1);
#pragma unroll
      for (int mf = 0; mf < 2; ++mf)
#pragma unroll
        for (int nf = 0; nf < 2; ++nf) {
          acc[mf][2 + nf] = __builtin_amdgcn_mfma_f32_16x16x32_bf16(aF[mf][0], bF1[nf][0], acc[mf][2 + nf], 0, 0, 0);
          acc[mf][2 + nf] = __builtin_amdgcn_mfma_f32_16x16x32_bf16(aF[mf][1], bF1[nf][1], acc[mf][2 + nf], 0, 0, 0);
        }
      __builtin_amdgcn_s_setprio(0);
      __builtin_amdgcn_s_barrier();
      // ---- P3: read A-h1; stage A-h0(t+2); MFMA Q(23,01)
#pragma unroll
      for (int mf = 0; mf < 2; ++mf)
#pragma unroll
        for (int kk = 0; kk < 2; ++kk) aF[mf][kk] = *(const short8*)(Lb + aFo[2 + mf][kk]);
      stA(u + 2, 0, u & 1);
      __builtin_amdgcn_s_barrier();
      asm volatile("s_waitcnt lgkmcnt(0)" ::: "memory");
      __builtin_amdgcn_s_setprio(1);
#pragma unroll
      for (int mf = 0; mf < 2; ++mf)
#pragma unroll
        for (int nf = 0; nf < 2; ++nf) {
          acc[2 + mf][nf] = __builtin_amdgcn_mfma_f32_16x16x32_bf16(aF[mf][0], bF0[nf][0], acc[2 + mf][nf], 0, 0, 0);
          acc[2 + mf][nf] = __builtin_amdgcn_mfma_f32_16x16x32_bf16(aF[mf][1], bF0[nf][1], acc[2 + mf][nf], 0, 0, 0);
        }
      __builtin_amdgcn_s_setprio(0);
      __builtin_amdgcn_s_barrier();
      // ---- P4: MFMA Q(23,23); stage B-h0(t+2); counted vmcnt
      stB(u + 2, 0, u & 1);
      __builtin_amdgcn_s_barrier();
      asm volatile("s_waitcnt lgkmcnt(0)" ::: "memory");
      __builtin_amdgcn_s_setprio(1);
#pragma unroll
      for (int mf = 0; mf < 2; ++mf)
#pragma unroll
        for (int nf = 0; nf < 2; ++nf) {
          acc[2 + mf][2 + nf] = __builtin_amdgcn_mfma_f32_16x16x32_bf16(aF[mf][0], bF1[nf][0], acc[2 + mf][2 + nf], 0, 0, 0);
          acc[2 + mf][2 + nf] = __builtin_amdgcn_mfma_f32_16x16x32_bf16(aF[mf][1], bF1[nf][1], acc[2 + mf][2 + nf], 0, 0, 0);
        }
      __builtin_amdgcn_s_setprio(0);
      asm volatile("s_waitcnt vmcnt(4)" ::: "memory");
      __builtin_amdgcn_s_barrier();
    }
#pragma unroll
    for (int j = 0; j < 2; ++j) { aSp[j] += 128; bSp[j] += 128; }
  }

  // epilogue
#pragma unroll
  for (int mf = 0; mf < 4; ++mf) {
    int r0 = tm + wm * 64 + mf * 16 + lg * 4;
#pragma unroll
    for (int nf = 0; nf < 4; ++nf) {
      int c2 = tn + wn * 64 + nf * 16 + lr;
      f32x4 v = acc[mf][nf];
#pragma unroll
      for (int j = 0; j < 4; ++j) {
        int r = r0 + j;
        if constexpr (EPI == 1) {
          ((u16*)outp)[(size_t)r * N + c2] = f2b(v[j]);
        } else if constexpr (EPI == 2) {
          float xv = v[j] + bias[c2];
          ((float*)outp)[(size_t)r * N + c2] = (xv > 20.f) ? xv : log1pf(__expf(xv));
        } else if constexpr (EPI == 3) {
          int bb = r >> 11, tt2 = r & (SEQL - 1);
          size_t oi = ((size_t)(bb * N + c2)) * SEQL + tt2;
          ((float*)outp)[oi] = v[j] + resid[oi];
        } else {
          ((float*)outp)[(size_t)r * N + c2] = v[j];
        }
      }
    }
  }
}

// ---- depthwise causal conv(k=4) + bias + silu; 2 d-lanes per thread
__global__ __launch_bounds__(256) void k_conv_silu(
    const u16* __restrict__ xz, const float* __restrict__ cw,
    const float* __restrict__ cb, u16* __restrict__ xbt) {
  size_t idx = (size_t)blockIdx.x * 256 + threadIdx.x;  // B*L*DINNER/2
  int d2 = (int)(idx & (DINNER / 2 - 1));
  int d = d2 * 2;
  int l = (int)((idx >> 10) & (SEQL - 1));
  int b = (int)(idx >> 21);
  f32x4 w0 = *(const f32x4*)&cw[d * 4];
  f32x4 w1 = *(const f32x4*)&cw[d * 4 + 4];
  float a0 = cb[d], a1 = cb[d + 1];
  size_t base = ((size_t)b * SEQL + l) * 4096 + d;
#pragma unroll
  for (int i = 0; i < 4; ++i) {
    int ls = l - 3 + i;
    if (ls >= 0) {
      unsigned int pv = *(const unsigned int*)&xz[base + (size_t)(i - 3) * 4096];
      a0 += w0[i] * b2f((u16)(pv & 0xFFFF));
      a1 += w1[i] * b2f((u16)(pv >> 16));
    }
  }
  float s0 = a0 / (1.f + __expf(-a0));
  float s1 = a1 / (1.f + __expf(-a1));
  unsigned int ov = (unsigned int)f2b(s0) | ((unsigned int)f2b(s1) << 16);
  *(unsigned int*)&xbt[((size_t)b * SEQL + l) * DINNER + d] = ov;
}

// ---- split-K MFMA skinny GEMM: bcp[ks][r][j] = sum_{k in chunk} xbt[r,k]*WxBCT[j,k]
__global__ __launch_bounds__(256) void k_bc_mfma(
    const u16* __restrict__ xbt, const u16* __restrict__ WxBCT,
    float* __restrict__ bcp) {
  __shared__ u16 As[128 * 32];
  int tid = threadIdx.x;
  int w = tid >> 6, lane = tid & 63;
  int tm = blockIdx.x * 128;
  int k0 = blockIdx.y * KCH;
  int lg = lane >> 4, lr = lane & 15;
  int srow = lane >> 2, scol = (lane & 3) * 8;

  f32x4 acc[2][2] = {};

  for (int kk = k0; kk < k0 + KCH; kk += 32) {
#pragma unroll
    for (int j = 0; j < 2; ++j) {
      int ch = w * 2 + j;
      const u16* ga = xbt + (size_t)(tm + ch * 16 + srow) * DINNER + kk + scol;
      __builtin_amdgcn_global_load_lds(
          (const __attribute__((address_space(1))) void*)ga,
          (__attribute__((address_space(3))) void*)&As[ch * 512], 16, 0, 0);
    }
    __syncthreads();
    short8 aF[2], bF[2];
#pragma unroll
    for (int m = 0; m < 2; ++m)
      aF[m] = *(const short8*)&As[(w * 32 + m * 16 + lr) * 32 + lg * 8];
#pragma unroll
    for (int n = 0; n < 2; ++n)
      bF[n] = *(const short8*)&WxBCT[(size_t)(n * 16 + lr) * DINNER + kk + lg * 8];
#pragma unroll
    for (int m = 0; m < 2; ++m)
#pragma unroll
      for (int n = 0; n < 2; ++n)
        acc[m][n] = __builtin_amdgcn_mfma_f32_16x16x32_bf16(aF[m], bF[n], acc[m][n], 0, 0, 0);
    __syncthreads();
  }

  float* outp = bcp + (size_t)blockIdx.y * (4096 * 32);
#pragma unroll
  for (int m = 0; m < 2; ++m) {
    int r0 = tm + w * 32 + m * 16 + lg * 4;
#pragma unroll
    for (int n = 0; n < 2; ++n) {
      int c = n * 16 + lr;
      f32x4 v = acc[m][n];
#pragma unroll
      for (int j = 0; j < 4; ++j)
        outp[(size_t)(r0 + j) * 32 + c] = v[j];
    }
  }
}

// ---- reduce split-K partials
__global__ __launch_bounds__(256) void k_bc_red(
    const float* __restrict__ bcp, float* __restrict__ bc) {
  size_t i = (size_t)blockIdx.x * 256 + threadIdx.x;
  float s = 0.f;
#pragma unroll
  for (int ks = 0; ks < KS; ++ks)
    s += bcp[(size_t)ks * (4096 * 32) + i];
  bc[i] = s;
}

// ==== chunked selective scan ====
__global__ __launch_bounds__(256) void k_scan_p1(
    const float* __restrict__ dlt, const u16* __restrict__ ub,
    const float* __restrict__ bcv, const float* __restrict__ A_log,
    float* __restrict__ Pc, float* __restrict__ Qc) {
  int d = blockIdx.x * 256 + threadIdx.x;
  int c = blockIdx.y;
  int b = blockIdx.z;
  float Av[16];
#pragma unroll
  for (int sv = 0; sv < 4; ++sv) {
    f32x4 al = *(const f32x4*)&A_log[d * 16 + sv * 4];
#pragma unroll
    for (int j = 0; j < 4; ++j) Av[sv * 4 + j] = -__expf(al[j]);
  }
  float P[16], Q[16];
#pragma unroll
  for (int s = 0; s < 16; ++s) { P[s] = 1.f; Q[s] = 0.f; }
  size_t row0 = (size_t)b * SEQL + (size_t)c * TC;
  for (int t = 0; t < TC; ++t) {
    size_t row = row0 + t;
    float dl = dlt[row * DINNER + d];
    float uu = b2f(ub[row * DINNER + d]);
    float bco = dl * uu;
    const f32x4* Bp = (const f32x4*)&bcv[row * 32];
#pragma unroll
    for (int sv = 0; sv < 4; ++sv) {
      f32x4 Bv = Bp[sv];
#pragma unroll
      for (int j = 0; j < 4; ++j) {
        int s = sv * 4 + j;
        float dA = __expf(dl * Av[s]);
        P[s] *= dA;
        Q[s] = dA * Q[s] + bco * Bv[j];
      }
    }
  }
  size_t base = (((size_t)b * NC + c) * DINNER + d) * 16;
#pragma unroll
  for (int sv = 0; sv < 4; ++sv) {
    f32x4 pv, qv;
#pragma unroll
    for (int j = 0; j < 4; ++j) { pv[j] = P[sv * 4 + j]; qv[j] = Q[sv * 4 + j]; }
    *(f32x4*)&Pc[base + sv * 4] = pv;
    *(f32x4*)&Qc[base + sv * 4] = qv;
  }
}

__global__ __launch_bounds__(256) void k_scan_p2(
    const float* __restrict__ Pc, const float* __restrict__ Qc,
    float* __restrict__ Hs) {
  size_t gid = (size_t)blockIdx.x * 256 + threadIdx.x;
  size_t bds = gid & ((size_t)DINNER * 16 - 1);
  int b = (int)(gid >> 15);
  float h = 0.f;
  size_t cstride = (size_t)DINNER * 16;
  size_t base = (size_t)b * NC * cstride + bds;
  for (int c = 0; c < NC; ++c) {
    size_t idx = base + (size_t)c * cstride;
    Hs[idx] = h;
    h = Pc[idx] * h + Qc[idx];
  }
}

__global__ __launch_bounds__(256) void k_scan_p3(
    const float* __restrict__ dlt, const u16* __restrict__ ub,
    const float* __restrict__ bcv, const u16* __restrict__ xz,
    const float* __restrict__ A_log, const float* __restrict__ Dskip,
    const float* __restrict__ Hs, u16* __restrict__ yg) {
  int d = blockIdx.x * 256 + threadIdx.x;
  int c = blockIdx.y;
  int b = blockIdx.z;
  float Av[16];
#pragma unroll
  for (int sv = 0; sv < 4; ++sv) {
    f32x4 al = *(const f32x4*)&A_log[d * 16 + sv * 4];
#pragma unroll
    for (int j = 0; j < 4; ++j) Av[sv * 4 + j] = -__expf(al[j]);
  }
  float h[16];
  size_t hb = (((size_t)b * NC + c) * DINNER + d) * 16;
#pragma unroll
  for (int sv = 0; sv < 4; ++sv) {
    f32x4 hv = *(const f32x4*)&Hs[hb + sv * 4];
#pragma unroll
    for (int j = 0; j < 4; ++j) h[sv * 4 + j] = hv[j];
  }
  float Dsk = Dskip[d];
  size_t row0 = (size_t)b * SEQL + (size_t)c * TC;
  for (int t = 0; t < TC; ++t) {
    size_t row = row0 + t;
    float dl = dlt[row * DINNER + d];
    float uu = b2f(ub[row * DINNER + d]);
    float bco = dl * uu;
    const f32x4* BCp = (const f32x4*)&bcv[row * 32];
    float y = 0.f;
#pragma unroll
    for (int sv = 0; sv < 4; ++sv) {
      f32x4 Bv = BCp[sv];
      f32x4 Cv = BCp[4 + sv];
#pragma unroll
      for (int j = 0; j < 4; ++j) {
        int s = sv * 4 + j;
        float dA = __expf(dl * Av[s]);
        h[s] = dA * h[s] + bco * Bv[j];
        y += h[s] * Cv[j];
      }
    }
    float zv = b2f(xz[row * 4096 + DINNER + d]);
    float yv = (y + Dsk * uu) * (zv / (1.f + __expf(-zv)));
    yg[row * DINNER + d] = f2b(yv);
  }
}

extern "C" void kernel_launch(void* const* d_in, const int* in_sizes, int n_in,
                              void* d_out, int out_size, void* d_ws, size_t ws_size,
                              hipStream_t stream) {
  (void)in_sizes; (void)n_in; (void)out_size; (void)ws_size;
  const float* x      = (const float*)d_in[0];
  const float* ln_w   = (const float*)d_in[1];
  const float* ln_b   = (const float*)d_in[2];
  const float* W_in   = (const float*)d_in[3];
  const float* conv_w = (const float*)d_in[4];
  const float* conv_b = (const float*)d_in[5];
  const float* W_x    = (const float*)d_in[6];
  const float* W_dt   = (const float*)d_in[7];
  const float* b_dt   = (const float*)d_in[8];
  const float* A_log  = (const float*)d_in[9];
  const float* Dskip  = (const float*)d_in[10];
  const float* W_out  = (const float*)d_in[11];
  float* out = (float*)d_out;

  char* ws = (char*)d_ws;
  const size_t MB = 1048576;
  u16*  xt    = (u16*)(ws + 0 * MB);     //  8 MB bf16; dead after LN
  u16*  xn    = (u16*)(ws + 8 * MB);     //  8 MB bf16; dead after xz gemm
  u16*  WinT  = (u16*)(ws + 16 * MB);    //  8 MB bf16 (4096,1024)
  u16*  WdtT  = (u16*)(ws + 32 * MB);    //  8 MB bf16 (2048,2048)
  u16*  WoutT = (u16*)(ws + 40 * MB);    //  4 MB bf16 (1024,2048)
  u16*  xz    = (u16*)(ws + 44 * MB);    // 32 MB bf16 (B*L, 4096)
  u16*  xbt   = (u16*)(ws + 76 * MB);    // 16 MB bf16 (B*L, DINNER)
  float* bc   = (float*)(ws + 92 * MB);  // 0.5 MB f32 (B*L, 32)
  u16*  WxRaw = (u16*)(ws + 93 * MB);    //  8 MB bf16 W_x[:,32:] row-major
  u16*  W_cT  = (u16*)(ws + 101 * MB);   //  8 MB bf16 combined weight (N,K)
  float* dlt  = (float*)(ws + 109 * MB); // 32 MB f32 (B*L, DINNER)
  float* Pc   = (float*)(ws + 141 * MB); //  8 MB
  float* Qc   = (float*)(ws + 149 * MB); //  8 MB
  float* Hs   = (float*)(ws + 157 * MB); //  8 MB
  float* bcp  = (float*)(ws + 165 * MB); //  8 MB split-K partials
  u16*  WxBCT = (u16*)(ws + 173 * MB);   // 128 KB bf16 (32,2048)
  u16*  yg    = (u16*)(ws + 0 * MB);     // 16 MB bf16, aliases xt+xn (dead)

  dim3 tb(32, 8);
  for (int b = 0; b < 2; ++b)
    k_transpose_cvt<<<dim3(SEQL / 32, DMODEL / 32), tb, 0, stream>>>(
        x + (size_t)b * DMODEL * SEQL, xt + (size_t)b * SEQL * DMODEL, DMODEL, SEQL, 0);
  k_transpose_cvt<<<dim3(4096 / 32, 1024 / 32), tb, 0, stream>>>(W_in, WinT, 1024, 4096, 0);
  k_transpose_cvt<<<dim3(1, 2048 / 32), tb, 0, stream>>>(W_x, WxBCT, 2048, 2080, 0);
  k_transpose_cvt<<<dim3(2048 / 32, 2048 / 32), tb, 0, stream>>>(W_dt, WdtT, 2048, 2048, 0);
  k_transpose_cvt<<<dim3(1024 / 32, 2048 / 32), tb, 0, stream>>>(W_out, WoutT, 2048, 1024, 0);
  k_cvt_rows<<<4096, 256, 0, stream>>>(W_x, WxRaw);

  // W_cT[n,k] = (Wx' @ W_dt)[k,n] : A=WdtT, BT=WxRaw, 2048^3; grid 16x16, chunk 4x4
  gemm8p<1><<<256, 256, 0, stream>>>(WdtT, WxRaw, W_cT, nullptr, nullptr, 2048, 2048, 2048, 4, 4);

  k_layernorm<<<4096, 256, 0, stream>>>(xt, ln_w, ln_b, xn);

  // xz = xn @ W_in   (4096 x 4096, K=1024); grid 32x32, chunk 8x8 (4 MB/L2)
  gemm8p<1><<<1024, 256, 0, stream>>>(xn, WinT, xz, nullptr, nullptr, 4096, 4096, 1024, 8, 8);

  k_conv_silu<<<16384, 256, 0, stream>>>(xz, conv_w, conv_b, xbt);

  // bc = xbt @ W_x[:, :32]
  k_bc_mfma<<<dim3(4096 / 128, KS), 256, 0, stream>>>(xbt, WxBCT, bcp);
  k_bc_red<<<131072 / 256, 256, 0, stream>>>(bcp, bc);

  // dlt = softplus(xbt @ W_c + b_dt); grid 32x16, chunk 4x4
  gemm8p<2><<<512, 256, 0, stream>>>(xbt, W_cT, dlt, b_dt, nullptr, 4096, 2048, 2048, 4, 4);

  // chunked scan
  k_scan_p1<<<dim3(DINNER / 256, NC, 2), 256, 0, stream>>>(dlt, xbt, bc, A_log, Pc, Qc);
  k_scan_p2<<<256, 256, 0, stream>>>(Pc, Qc, Hs);
  k_scan_p3<<<dim3(DINNER / 256, NC, 2), 256, 0, stream>>>(
      dlt, xbt, bc, xz, A_log, Dskip, Hs, yg);

  // out = yg @ W_out, transposed + residual; grid 32x8, chunk 4x4
  gemm8p<3><<<256, 256, 0, stream>>>(yg, WoutT, out, nullptr, x, 4096, 1024, 2048, 4, 4);
}

// Round 10
// 305.832 us; speedup vs baseline: 1.3439x; 1.0014x over previous
//
#include <hip/hip_runtime.h>
#include <cstdint>
#include <cstddef>

#define SEQL 2048
#define DMODEL 1024
#define DINNER 2048
#define NSTATE 16
#define NC 32          // scan chunks
#define TC 64          // SEQL / NC
#define KS 16          // k_bc split-K chunks
#define KCH 128        // DINNER / KS

typedef __attribute__((ext_vector_type(4))) float f32x4;
typedef __attribute__((ext_vector_type(8))) short short8;
typedef __attribute__((ext_vector_type(4))) short short4v;
typedef unsigned short u16;

__device__ __forceinline__ float b2f(u16 u) {
  union { unsigned int i; float f; } v; v.i = ((unsigned int)u) << 16; return v.f;
}
__device__ __forceinline__ u16 f2b(float f) {
  union { float f; unsigned int i; } v; v.f = f;
  unsigned int r = v.i + 0x7FFFu + ((v.i >> 16) & 1u);
  return (u16)(r >> 16);
}

// ---- transpose + fp32->bf16 : out[c][r] = in[r][c0+c], out is (Cout x R)
__global__ __launch_bounds__(256) void k_transpose_cvt(
    const float* __restrict__ in, u16* __restrict__ out, int R, int C, int c0) {
  __shared__ float t[32][33];
  int cb = blockIdx.x * 32, rb = blockIdx.y * 32;
  int tx = threadIdx.x, ty = threadIdx.y;
#pragma unroll
  for (int i = 0; i < 32; i += 8)
    t[ty + i][tx] = in[(size_t)(rb + ty + i) * C + c0 + cb + tx];
  __syncthreads();
#pragma unroll
  for (int i = 0; i < 32; i += 8)
    out[(size_t)(cb + ty + i) * R + rb + tx] = f2b(t[tx][ty + i]);
}

// ---- straight row-convert: WxRaw[r][c] = bf16(W_x[r][32+c]), 2048x2048
__global__ __launch_bounds__(256) void k_cvt_rows(
    const float* __restrict__ in, u16* __restrict__ out) {
  size_t idx = (size_t)blockIdx.x * 256 + threadIdx.x;  // elems/4
  size_t i4 = idx * 4;
  int r = (int)(i4 >> 11), c = (int)(i4 & 2047);
  f32x4 v = *(const f32x4*)&in[(size_t)r * 2080 + 32 + c];
  short4v o;
#pragma unroll
  for (int j = 0; j < 4; ++j) o[j] = (short)f2b(v[j]);
  *(short4v*)&out[i4] = o;
}

// ---- LayerNorm over DMODEL, rows = B*L, bf16 in -> bf16 out
__global__ __launch_bounds__(256) void k_layernorm(
    const u16* __restrict__ xt, const float* __restrict__ w,
    const float* __restrict__ b, u16* __restrict__ xn) {
  int row = blockIdx.x;
  const u16* px = xt + (size_t)row * DMODEL;
  int i4 = threadIdx.x * 4;
  short4v sv = *(const short4v*)&px[i4];
  float v[4];
#pragma unroll
  for (int j = 0; j < 4; ++j) v[j] = b2f((u16)sv[j]);
  float s1 = v[0] + v[1] + v[2] + v[3];
  float s2 = v[0]*v[0] + v[1]*v[1] + v[2]*v[2] + v[3]*v[3];
#pragma unroll
  for (int off = 32; off > 0; off >>= 1) {
    s1 += __shfl_xor(s1, off);
    s2 += __shfl_xor(s2, off);
  }
  __shared__ float a1[4], a2[4];
  int lane = threadIdx.x & 63, wid = threadIdx.x >> 6;
  if (lane == 0) { a1[wid] = s1; a2[wid] = s2; }
  __syncthreads();
  float t1 = a1[0] + a1[1] + a1[2] + a1[3];
  float t2 = a2[0] + a2[1] + a2[2] + a2[3];
  float mu = t1 * (1.f / DMODEL);
  float rs = rsqrtf(t2 * (1.f / DMODEL) - mu * mu + 1e-5f);
  short4v ov;
#pragma unroll
  for (int j = 0; j < 4; ++j) ov[j] = (short)f2b((v[j] - mu) * rs * w[i4 + j] + b[i4 + j]);
  *(short4v*)&xn[(size_t)row * DMODEL + i4] = ov;
}

// ==================== 256x256 8-phase MFMA GEMM (m201 geometry) ====================
// 512 threads = 8 waves (2M x 4N), per-wave 128x64 output, BK=64, 128 KiB LDS.
// bf16 store only. Requires grid (M/256)*(N/256) — use ONLY when that fills chip.
__global__ __launch_bounds__(512) void gemm8x(
    const u16* __restrict__ A, const u16* __restrict__ BT,
    u16* __restrict__ outp, int M, int N, int K) {
  constexpr int LDSTILE = 64 * 512;       // elems per buffer (A 256x64 + B 256x64)
  __shared__ u16 lds[2 * LDSTILE];        // 128 KiB

  const int tid = threadIdx.x;
  const int w = tid >> 6, lane = tid & 63;
  const int wm = w >> 2, wn = w & 3;
  const int lg = lane >> 4, lr = lane & 15;
  const int wbase = tid & ~63;

  const int gx = N / 256;
  const int cpx = gridDim.x >> 3;
  const int wg = ((int)blockIdx.x & 7) * cpx + ((int)blockIdx.x >> 3);
  const int tm = (wg / gx) * 256;
  const int tn = (wg % gx) * 256;
  const int NT = K >> 6;

  const u16* Ab = A + (size_t)tm * K;
  const u16* Bb = BT + (size_t)tn * K;

  auto stageA = [&](int tc, int h) {
    int tcl = tc < NT ? tc : NT - 1;
    const u16* g0 = Ab + (size_t)tcl * 64;
    u16* l0 = lds + (tc & 1) * LDSTILE;
#pragma unroll
    for (int j = 0; j < 2; ++j) {
      int t8 = j * 512 + tid;
      int r8 = t8 >> 3;
      int pr = (r8 & 63) + ((r8 >> 6) << 7) + h * 64;
      int sk = ((((t8 & 7) << 4) ^ ((pr & 7) << 4)) >> 1);
      int r8b = (j * 512 + wbase) >> 3;
      int prb = (r8b & 63) + ((r8b >> 6) << 7) + h * 64;
      __builtin_amdgcn_global_load_lds(
          (const __attribute__((address_space(1))) void*)(g0 + (size_t)pr * K + sk),
          (__attribute__((address_space(3))) void*)(l0 + prb * 64), 16, 0, 0);
    }
  };
  auto stageB = [&](int tc, int h) {
    int tcl = tc < NT ? tc : NT - 1;
    const u16* g0 = Bb + (size_t)tcl * 64;
    u16* l0 = lds + (tc & 1) * LDSTILE + 256 * 64;
#pragma unroll
    for (int j = 0; j < 2; ++j) {
      int t8 = j * 512 + tid;
      int r8 = t8 >> 3;
      int pr = (r8 % 32) + (r8 / 32) * 64 + h * 32;
      int sk = ((((t8 & 7) << 4) ^ ((pr & 7) << 4)) >> 1);
      int r8b = (j * 512 + wbase) >> 3;
      int prb = (r8b % 32) + (r8b / 32) * 64 + h * 32;
      __builtin_amdgcn_global_load_lds(
          (const __attribute__((address_space(1))) void*)(g0 + (size_t)pr * K + sk),
          (__attribute__((address_space(3))) void*)(l0 + prb * 64), 16, 0, 0);
    }
  };
  auto fragA = [&](const u16* base, int mf, int kk) -> short8 {
    int r = wm * 128 + mf * 16 + lr;
    int cb = (kk * 64 + lg * 16) ^ ((r & 7) << 4);
    return *(const short8*)((const char*)base + r * 128 + cb);
  };
  auto fragB = [&](const u16* base, int nf, int kk) -> short8 {
    int r = wn * 64 + nf * 16 + lr;
    int cb = (kk * 64 + lg * 16) ^ ((r & 7) << 4);
    return *(const short8*)((const char*)base + 256 * 128 + r * 128 + cb);
  };

  f32x4 acc[8][4] = {};
  short8 aF[4][2], bF0[2][2], bF1[2][2];

  stageA(0, 0); stageB(0, 0); stageB(0, 1); stageA(0, 1);
  stageA(1, 0); stageB(1, 0);
  asm volatile("s_waitcnt vmcnt(4)" ::: "memory");
  __builtin_amdgcn_s_barrier();

  for (int t = 0; t < NT; ++t) {
    const u16* Ac = lds + (t & 1) * LDSTILE;
    // P1: read A-h0 + B-h0; stage B1(t+1); MFMA Q(0,0)
#pragma unroll
    for (int mf = 0; mf < 4; ++mf) { aF[mf][0] = fragA(Ac, mf, 0); aF[mf][1] = fragA(Ac, mf, 1); }
#pragma unroll
    for (int nf = 0; nf < 2; ++nf) { bF0[nf][0] = fragB(Ac, nf, 0); bF0[nf][1] = fragB(Ac, nf, 1); }
    stageB(t + 1, 1);
    __builtin_amdgcn_s_barrier();
    asm volatile("s_waitcnt lgkmcnt(0)" ::: "memory");
    __builtin_amdgcn_s_setprio(1);
#pragma unroll
    for (int mf = 0; mf < 4; ++mf)
#pragma unroll
      for (int nf = 0; nf < 2; ++nf) {
        acc[mf][nf] = __builtin_amdgcn_mfma_f32_16x16x32_bf16(aF[mf][0], bF0[nf][0], acc[mf][nf], 0, 0, 0);
        acc[mf][nf] = __builtin_amdgcn_mfma_f32_16x16x32_bf16(aF[mf][1], bF0[nf][1], acc[mf][nf], 0, 0, 0);
      }
    __builtin_amdgcn_s_setprio(0);
    __builtin_amdgcn_s_barrier();
    // P2: read B-h1; stage A1(t+1); MFMA Q(0,1)
#pragma unroll
    for (int nf = 0; nf < 2; ++nf) { bF1[nf][0] = fragB(Ac, 2 + nf, 0); bF1[nf][1] = fragB(Ac, 2 + nf, 1); }
    stageA(t + 1, 1);
    __builtin_amdgcn_s_barrier();
    asm volatile("s_waitcnt lgkmcnt(0)" ::: "memory");
    __builtin_amdgcn_s_setprio(1);
#pragma unroll
    for (int mf = 0; mf < 4; ++mf)
#pragma unroll
      for (int nf = 0; nf < 2; ++nf) {
        acc[mf][2 + nf] = __builtin_amdgcn_mfma_f32_16x16x32_bf16(aF[mf][0], bF1[nf][0], acc[mf][2 + nf], 0, 0, 0);
        acc[mf][2 + nf] = __builtin_amdgcn_mfma_f32_16x16x32_bf16(aF[mf][1], bF1[nf][1], acc[mf][2 + nf], 0, 0, 0);
      }
    __builtin_amdgcn_s_setprio(0);
    __builtin_amdgcn_s_barrier();
    // P3: read A-h1; stage A0(t+2); MFMA Q(1,0)
#pragma unroll
    for (int mf = 0; mf < 4; ++mf) { aF[mf][0] = fragA(Ac, 4 + mf, 0); aF[mf][1] = fragA(Ac, 4 + mf, 1); }
    stageA(t + 2, 0);
    __builtin_amdgcn_s_barrier();
    asm volatile("s_waitcnt lgkmcnt(0)" ::: "memory");
    __builtin_amdgcn_s_setprio(1);
#pragma unroll
    for (int mf = 0; mf < 4; ++mf)
#pragma unroll
      for (int nf = 0; nf < 2; ++nf) {
        acc[4 + mf][nf] = __builtin_amdgcn_mfma_f32_16x16x32_bf16(aF[mf][0], bF0[nf][0], acc[4 + mf][nf], 0, 0, 0);
        acc[4 + mf][nf] = __builtin_amdgcn_mfma_f32_16x16x32_bf16(aF[mf][1], bF0[nf][1], acc[4 + mf][nf], 0, 0, 0);
      }
    __builtin_amdgcn_s_setprio(0);
    __builtin_amdgcn_s_barrier();
    // P4: MFMA Q(1,1); stage B0(t+2); counted vmcnt
    stageB(t + 2, 0);
    __builtin_amdgcn_s_barrier();
    asm volatile("s_waitcnt lgkmcnt(0)" ::: "memory");
    __builtin_amdgcn_s_setprio(1);
#pragma unroll
    for (int mf = 0; mf < 4; ++mf)
#pragma unroll
      for (int nf = 0; nf < 2; ++nf) {
        acc[4 + mf][2 + nf] = __builtin_amdgcn_mfma_f32_16x16x32_bf16(aF[mf][0], bF1[nf][0], acc[4 + mf][2 + nf], 0, 0, 0);
        acc[4 + mf][2 + nf] = __builtin_amdgcn_mfma_f32_16x16x32_bf16(aF[mf][1], bF1[nf][1], acc[4 + mf][2 + nf], 0, 0, 0);
      }
    __builtin_amdgcn_s_setprio(0);
    asm volatile("s_waitcnt vmcnt(4)" ::: "memory");
    __builtin_amdgcn_s_barrier();
  }

#pragma unroll
  for (int mf = 0; mf < 8; ++mf) {
    int r0 = tm + wm * 128 + mf * 16 + lg * 4;
#pragma unroll
    for (int nf = 0; nf < 4; ++nf) {
      int c = tn + wn * 64 + nf * 16 + lr;
      f32x4 v = acc[mf][nf];
#pragma unroll
      for (int j = 0; j < 4; ++j)
        outp[(size_t)(r0 + j) * N + c] = f2b(v[j]);
    }
  }
}

// ==================== 4-phase 128x128 MFMA GEMM, 2 blocks/CU ====================
// EPI: 1 bf16; 2 bf16 softplus(acc+bias[col]); 3 f32 transposed + residual.
template<int EPI>
__global__ __launch_bounds__(256) void gemm8p(
    const u16* __restrict__ A, const u16* __restrict__ BT,
    void* __restrict__ outp, const float* __restrict__ bias,
    const float* __restrict__ resid, int M, int N, int K) {
  constexpr int LDSTILE = 2 * 128 * 64;   // elems per buffer (A + B)
  __shared__ u16 lds[2 * LDSTILE];        // 64 KiB

  const int tid = threadIdx.x;
  const int w = tid >> 6, lane = tid & 63;
  const int wm = w >> 1, wn = w & 1;
  const int lg = lane >> 4, lr = lane & 15;
  const int wbase = tid & ~63;

  const int gx = N / 128;
  const int cpx = gridDim.x >> 3;
  const int wg = ((int)blockIdx.x & 7) * cpx + ((int)blockIdx.x >> 3);
  const int tm = (wg / gx) * 128;
  const int tn = (wg % gx) * 128;
  const int NT = K >> 6;

  const u16* aSp[2];
  const u16* bSp[2];
  int aD[2], bD[2];
#pragma unroll
  for (int j = 0; j < 2; ++j) {
    int t8 = j * 256 + tid;
    int r8 = t8 >> 3;
    int pr = (r8 & 31) + ((r8 >> 5) << 6);
    int sk = ((((t8 & 7) << 4) ^ ((pr & 7) << 4)) >> 1);
    aSp[j] = A + (size_t)(tm + pr) * K + sk;
    bSp[j] = BT + (size_t)(tn + pr) * K + sk;
    int r8b = (j * 256 + wbase) >> 3;
    int prb = (r8b & 31) + ((r8b >> 5) << 6);
    aD[j] = prb * 64;
    bD[j] = 128 * 64 + prb * 64;
  }
  int aFo[4][2], bFo[4][2];
#pragma unroll
  for (int mf = 0; mf < 4; ++mf)
#pragma unroll
    for (int kk = 0; kk < 2; ++kk) {
      int r = wm * 64 + mf * 16 + lr;
      aFo[mf][kk] = r * 128 + ((kk * 64 + lg * 16) ^ ((r & 7) << 4));
      int rb = wn * 64 + mf * 16 + lr;
      bFo[mf][kk] = 128 * 64 * 2 + rb * 128 + ((kk * 64 + lg * 16) ^ ((rb & 7) << 4));
    }

  auto stA = [&](int toff, int h, int buf) {
#pragma unroll
    for (int j = 0; j < 2; ++j)
      __builtin_amdgcn_global_load_lds(
          (const __attribute__((address_space(1))) void*)(aSp[j] + toff * 64 + h * (K << 5)),
          (__attribute__((address_space(3))) void*)(lds + buf * LDSTILE + aD[j] + h * 2048),
          16, 0, 0);
  };
  auto stB = [&](int toff, int h, int buf) {
#pragma unroll
    for (int j = 0; j < 2; ++j)
      __builtin_amdgcn_global_load_lds(
          (const __attribute__((address_space(1))) void*)(bSp[j] + toff * 64 + h * (K << 5)),
          (__attribute__((address_space(3))) void*)(lds + buf * LDSTILE + bD[j] + h * 2048),
          16, 0, 0);
  };

  f32x4 acc[4][4] = {};
  short8 aF[2][2], bF0[2][2], bF1[2][2];

  stA(0, 0, 0); stB(0, 0, 0); stB(0, 1, 0); stA(0, 1, 0);
  stA(1, 0, 1); stB(1, 0, 1);
  asm volatile("s_waitcnt vmcnt(4)" ::: "memory");
  __builtin_amdgcn_s_barrier();

  for (int tt = 0; tt < NT; tt += 2) {
#pragma unroll
    for (int u = 0; u < 2; ++u) {
      const char* Lb = (const char*)lds + u * (LDSTILE * 2);
      // P1
#pragma unroll
      for (int mf = 0; mf < 2; ++mf)
#pragma unroll
        for (int kk = 0; kk < 2; ++kk) aF[mf][kk] = *(const short8*)(Lb + aFo[mf][kk]);
#pragma unroll
      for (int nf = 0; nf < 2; ++nf)
#pragma unroll
        for (int kk = 0; kk < 2; ++kk) bF0[nf][kk] = *(const short8*)(Lb + bFo[nf][kk]);
      stB(u + 1, 1, (u + 1) & 1);
      __builtin_amdgcn_s_barrier();
      asm volatile("s_waitcnt lgkmcnt(0)" ::: "memory");
      __builtin_amdgcn_s_setprio(1);
#pragma unroll
      for (int mf = 0; mf < 2; ++mf)
#pragma unroll
        for (int nf = 0; nf < 2; ++nf) {
          acc[mf][nf] = __builtin_amdgcn_mfma_f32_16x16x32_bf16(aF[mf][0], bF0[nf][0], acc[mf][nf], 0, 0, 0);
          acc[mf][nf] = __builtin_amdgcn_mfma_f32_16x16x32_bf16(aF[mf][1], bF0[nf][1], acc[mf][nf], 0, 0, 0);
        }
      __builtin_amdgcn_s_setprio(0);
      __builtin_amdgcn_s_barrier();
      // P2
#pragma unroll
      for (int nf = 0; nf < 2; ++nf)
#pragma unroll
        for (int kk = 0; kk < 2; ++kk) bF1[nf][kk] = *(const short8*)(Lb + bFo[2 + nf][kk]);
      stA(u + 1, 1, (u + 1) & 1);
      __builtin_amdgcn_s_barrier();
      asm volatile("s_waitcnt lgkmcnt(0)" ::: "memory");
      __builtin_amdgcn_s_setprio(1);
#pragma unroll
      for (int mf = 0; mf < 2; ++mf)
#pragma unroll
        for (int nf = 0; nf < 2; ++nf) {
          acc[mf][2 + nf] = __builtin_amdgcn_mfma_f32_16x16x32_bf16(aF[mf][0], bF1[nf][0], acc[mf][2 + nf], 0, 0, 0);
          acc[mf][2 + nf] = __builtin_amdgcn_mfma_f32_16x16x32_bf16(aF[mf][1], bF1[nf][1], acc[mf][2 + nf], 0, 0, 0);
        }
      __builtin_amdgcn_s_setprio(0);
      __builtin_amdgcn_s_barrier();
      // P3
#pragma unroll
      for (int mf = 0; mf < 2; ++mf)
#pragma unroll
        for (int kk = 0; kk < 2; ++kk) aF[mf][kk] = *(const short8*)(Lb + aFo[2 + mf][kk]);
      stA(u + 2, 0, u & 1);
      __builtin_amdgcn_s_barrier();
      asm volatile("s_waitcnt lgkmcnt(0)" ::: "memory");
      __builtin_amdgcn_s_setprio(1);
#pragma unroll
      for (int mf = 0; mf < 2; ++mf)
#pragma unroll
        for (int nf = 0; nf < 2; ++nf) {
          acc[2 + mf][nf] = __builtin_amdgcn_mfma_f32_16x16x32_bf16(aF[mf][0], bF0[nf][0], acc[2 + mf][nf], 0, 0, 0);
          acc[2 + mf][nf] = __builtin_amdgcn_mfma_f32_16x16x32_bf16(aF[mf][1], bF0[nf][1], acc[2 + mf][nf], 0, 0, 0);
        }
      __builtin_amdgcn_s_setprio(0);
      __builtin_amdgcn_s_barrier();
      // P4
      stB(u + 2, 0, u & 1);
      __builtin_amdgcn_s_barrier();
      asm volatile("s_waitcnt lgkmcnt(0)" ::: "memory");
      __builtin_amdgcn_s_setprio(1);
#pragma unroll
      for (int mf = 0; mf < 2; ++mf)
#pragma unroll
        for (int nf = 0; nf < 2; ++nf) {
          acc[2 + mf][2 + nf] = __builtin_amdgcn_mfma_f32_16x16x32_bf16(aF[mf][0], bF1[nf][0], acc[2 + mf][2 + nf], 0, 0, 0);
          acc[2 + mf][2 + nf] = __builtin_amdgcn_mfma_f32_16x16x32_bf16(aF[mf][1], bF1[nf][1], acc[2 + mf][2 + nf], 0, 0, 0);
        }
      __builtin_amdgcn_s_setprio(0);
      asm volatile("s_waitcnt vmcnt(4)" ::: "memory");
      __builtin_amdgcn_s_barrier();
    }
#pragma unroll
    for (int j = 0; j < 2; ++j) { aSp[j] += 128; bSp[j] += 128; }
  }

#pragma unroll
  for (int mf = 0; mf < 4; ++mf) {
    int r0 = tm + wm * 64 + mf * 16 + lg * 4;
#pragma unroll
    for (int nf = 0; nf < 4; ++nf) {
      int c2 = tn + wn * 64 + nf * 16 + lr;
      f32x4 v = acc[mf][nf];
#pragma unroll
      for (int j = 0; j < 4; ++j) {
        int r = r0 + j;
        if constexpr (EPI == 1) {
          ((u16*)outp)[(size_t)r * N + c2] = f2b(v[j]);
        } else if constexpr (EPI == 2) {
          float xv = v[j] + bias[c2];
          float sp = (xv > 20.f) ? xv : log1pf(__expf(xv));
          ((u16*)outp)[(size_t)r * N + c2] = f2b(sp);
        } else if constexpr (EPI == 3) {
          int bb = r >> 11, tt2 = r & (SEQL - 1);
          size_t oi = ((size_t)(bb * N + c2)) * SEQL + tt2;
          ((float*)outp)[oi] = v[j] + resid[oi];
        } else {
          ((float*)outp)[(size_t)r * N + c2] = v[j];
        }
      }
    }
  }
}

// ---- depthwise causal conv(k=4) + bias + silu; 2 d-lanes per thread
__global__ __launch_bounds__(256) void k_conv_silu(
    const u16* __restrict__ xz, const float* __restrict__ cw,
    const float* __restrict__ cb, u16* __restrict__ xbt) {
  size_t idx = (size_t)blockIdx.x * 256 + threadIdx.x;
  int d2 = (int)(idx & (DINNER / 2 - 1));
  int d = d2 * 2;
  int l = (int)((idx >> 10) & (SEQL - 1));
  int b = (int)(idx >> 21);
  f32x4 w0 = *(const f32x4*)&cw[d * 4];
  f32x4 w1 = *(const f32x4*)&cw[d * 4 + 4];
  float a0 = cb[d], a1 = cb[d + 1];
  size_t base = ((size_t)b * SEQL + l) * 4096 + d;
#pragma unroll
  for (int i = 0; i < 4; ++i) {
    int ls = l - 3 + i;
    if (ls >= 0) {
      unsigned int pv = *(const unsigned int*)&xz[base + (size_t)(i - 3) * 4096];
      a0 += w0[i] * b2f((u16)(pv & 0xFFFF));
      a1 += w1[i] * b2f((u16)(pv >> 16));
    }
  }
  float s0 = a0 / (1.f + __expf(-a0));
  float s1 = a1 / (1.f + __expf(-a1));
  unsigned int ov = (unsigned int)f2b(s0) | ((unsigned int)f2b(s1) << 16);
  *(unsigned int*)&xbt[((size_t)b * SEQL + l) * DINNER + d] = ov;
}

// ---- split-K MFMA skinny GEMM
__global__ __launch_bounds__(256) void k_bc_mfma(
    const u16* __restrict__ xbt, const u16* __restrict__ WxBCT,
    float* __restrict__ bcp) {
  __shared__ u16 As[128 * 32];
  int tid = threadIdx.x;
  int w = tid >> 6, lane = tid & 63;
  int tm = blockIdx.x * 128;
  int k0 = blockIdx.y * KCH;
  int lg = lane >> 4, lr = lane & 15;
  int srow = lane >> 2, scol = (lane & 3) * 8;

  f32x4 acc[2][2] = {};

  for (int kk = k0; kk < k0 + KCH; kk += 32) {
#pragma unroll
    for (int j = 0; j < 2; ++j) {
      int ch = w * 2 + j;
      const u16* ga = xbt + (size_t)(tm + ch * 16 + srow) * DINNER + kk + scol;
      __builtin_amdgcn_global_load_lds(
          (const __attribute__((address_space(1))) void*)ga,
          (__attribute__((address_space(3))) void*)&As[ch * 512], 16, 0, 0);
    }
    __syncthreads();
    short8 aF[2], bF[2];
#pragma unroll
    for (int m = 0; m < 2; ++m)
      aF[m] = *(const short8*)&As[(w * 32 + m * 16 + lr) * 32 + lg * 8];
#pragma unroll
    for (int n = 0; n < 2; ++n)
      bF[n] = *(const short8*)&WxBCT[(size_t)(n * 16 + lr) * DINNER + kk + lg * 8];
#pragma unroll
    for (int m = 0; m < 2; ++m)
#pragma unroll
      for (int n = 0; n < 2; ++n)
        acc[m][n] = __builtin_amdgcn_mfma_f32_16x16x32_bf16(aF[m], bF[n], acc[m][n], 0, 0, 0);
    __syncthreads();
  }

  float* outp = bcp + (size_t)blockIdx.y * (4096 * 32);
#pragma unroll
  for (int m = 0; m < 2; ++m) {
    int r0 = tm + w * 32 + m * 16 + lg * 4;
#pragma unroll
    for (int n = 0; n < 2; ++n) {
      int c = n * 16 + lr;
      f32x4 v = acc[m][n];
#pragma unroll
      for (int j = 0; j < 4; ++j)
        outp[(size_t)(r0 + j) * 32 + c] = v[j];
    }
  }
}

__global__ __launch_bounds__(256) void k_bc_red(
    const float* __restrict__ bcp, float* __restrict__ bc) {
  size_t i = (size_t)blockIdx.x * 256 + threadIdx.x;
  float s = 0.f;
#pragma unroll
  for (int ks = 0; ks < KS; ++ks)
    s += bcp[(size_t)ks * (4096 * 32) + i];
  bc[i] = s;
}

// ==== chunked selective scan (dlt now bf16) ====
__global__ __launch_bounds__(256) void k_scan_p1(
    const u16* __restrict__ dlt, const u16* __restrict__ ub,
    const float* __restrict__ bcv, const float* __restrict__ A_log,
    float* __restrict__ Pc, float* __restrict__ Qc) {
  int d = blockIdx.x * 256 + threadIdx.x;
  int c = blockIdx.y;
  int b = blockIdx.z;
  float Av[16];
#pragma unroll
  for (int sv = 0; sv < 4; ++sv) {
    f32x4 al = *(const f32x4*)&A_log[d * 16 + sv * 4];
#pragma unroll
    for (int j = 0; j < 4; ++j) Av[sv * 4 + j] = -__expf(al[j]);
  }
  float P[16], Q[16];
#pragma unroll
  for (int s = 0; s < 16; ++s) { P[s] = 1.f; Q[s] = 0.f; }
  size_t row0 = (size_t)b * SEQL + (size_t)c * TC;
  for (int t = 0; t < TC; ++t) {
    size_t row = row0 + t;
    float dl = b2f(dlt[row * DINNER + d]);
    float uu = b2f(ub[row * DINNER + d]);
    float bco = dl * uu;
    const f32x4* Bp = (const f32x4*)&bcv[row * 32];
#pragma unroll
    for (int sv = 0; sv < 4; ++sv) {
      f32x4 Bv = Bp[sv];
#pragma unroll
      for (int j = 0; j < 4; ++j) {
        int s = sv * 4 + j;
        float dA = __expf(dl * Av[s]);
        P[s] *= dA;
        Q[s] = dA * Q[s] + bco * Bv[j];
      }
    }
  }
  size_t base = (((size_t)b * NC + c) * DINNER + d) * 16;
#pragma unroll
  for (int sv = 0; sv < 4; ++sv) {
    f32x4 pv, qv;
#pragma unroll
    for (int j = 0; j < 4; ++j) { pv[j] = P[sv * 4 + j]; qv[j] = Q[sv * 4 + j]; }
    *(f32x4*)&Pc[base + sv * 4] = pv;
    *(f32x4*)&Qc[base + sv * 4] = qv;
  }
}

__global__ __launch_bounds__(256) void k_scan_p2(
    const float* __restrict__ Pc, const float* __restrict__ Qc,
    float* __restrict__ Hs) {
  size_t gid = (size_t)blockIdx.x * 256 + threadIdx.x;
  size_t bds = gid & ((size_t)DINNER * 16 - 1);
  int b = (int)(gid >> 15);
  float h = 0.f;
  size_t cstride = (size_t)DINNER * 16;
  size_t base = (size_t)b * NC * cstride + bds;
  for (int c = 0; c < NC; ++c) {
    size_t idx = base + (size_t)c * cstride;
    Hs[idx] = h;
    h = Pc[idx] * h + Qc[idx];
  }
}

__global__ __launch_bounds__(256) void k_scan_p3(
    const u16* __restrict__ dlt, const u16* __restrict__ ub,
    const float* __restrict__ bcv, const u16* __restrict__ xz,
    const float* __restrict__ A_log, const float* __restrict__ Dskip,
    const float* __restrict__ Hs, u16* __restrict__ yg) {
  int d = blockIdx.x * 256 + threadIdx.x;
  int c = blockIdx.y;
  int b = blockIdx.z;
  float Av[16];
#pragma unroll
  for (int sv = 0; sv < 4; ++sv) {
    f32x4 al = *(const f32x4*)&A_log[d * 16 + sv * 4];
#pragma unroll
    for (int j = 0; j < 4; ++j) Av[sv * 4 + j] = -__expf(al[j]);
  }
  float h[16];
  size_t hb = (((size_t)b * NC + c) * DINNER + d) * 16;
#pragma unroll
  for (int sv = 0; sv < 4; ++sv) {
    f32x4 hv = *(const f32x4*)&Hs[hb + sv * 4];
#pragma unroll
    for (int j = 0; j < 4; ++j) h[sv * 4 + j] = hv[j];
  }
  float Dsk = Dskip[d];
  size_t row0 = (size_t)b * SEQL + (size_t)c * TC;
  for (int t = 0; t < TC; ++t) {
    size_t row = row0 + t;
    float dl = b2f(dlt[row * DINNER + d]);
    float uu = b2f(ub[row * DINNER + d]);
    float bco = dl * uu;
    const f32x4* BCp = (const f32x4*)&bcv[row * 32];
    float y = 0.f;
#pragma unroll
    for (int sv = 0; sv < 4; ++sv) {
      f32x4 Bv = BCp[sv];
      f32x4 Cv = BCp[4 + sv];
#pragma unroll
      for (int j = 0; j < 4; ++j) {
        int s = sv * 4 + j;
        float dA = __expf(dl * Av[s]);
        h[s] = dA * h[s] + bco * Bv[j];
        y += h[s] * Cv[j];
      }
    }
    float zv = b2f(xz[row * 4096 + DINNER + d]);
    float yv = (y + Dsk * uu) * (zv / (1.f + __expf(-zv)));
    yg[row * DINNER + d] = f2b(yv);
  }
}

extern "C" void kernel_launch(void* const* d_in, const int* in_sizes, int n_in,
                              void* d_out, int out_size, void* d_ws, size_t ws_size,
                              hipStream_t stream) {
  (void)in_sizes; (void)n_in; (void)out_size; (void)ws_size;
  const float* x      = (const float*)d_in[0];
  const float* ln_w   = (const float*)d_in[1];
  const float* ln_b   = (const float*)d_in[2];
  const float* W_in   = (const float*)d_in[3];
  const float* conv_w = (const float*)d_in[4];
  const float* conv_b = (const float*)d_in[5];
  const float* W_x    = (const float*)d_in[6];
  const float* W_dt   = (const float*)d_in[7];
  const float* b_dt   = (const float*)d_in[8];
  const float* A_log  = (const float*)d_in[9];
  const float* Dskip  = (const float*)d_in[10];
  const float* W_out  = (const float*)d_in[11];
  float* out = (float*)d_out;

  char* ws = (char*)d_ws;
  const size_t MB = 1048576;
  u16*  xt    = (u16*)(ws + 0 * MB);     //  8 MB bf16; dead after LN
  u16*  xn    = (u16*)(ws + 8 * MB);     //  8 MB bf16; dead after xz gemm
  u16*  WinT  = (u16*)(ws + 16 * MB);    //  8 MB bf16 (4096,1024)
  u16*  WdtT  = (u16*)(ws + 32 * MB);    //  8 MB bf16 (2048,2048)
  u16*  WoutT = (u16*)(ws + 40 * MB);    //  4 MB bf16 (1024,2048)
  u16*  xz    = (u16*)(ws + 44 * MB);    // 32 MB bf16 (B*L, 4096)
  u16*  xbt   = (u16*)(ws + 76 * MB);    // 16 MB bf16 (B*L, DINNER)
  float* bc   = (float*)(ws + 92 * MB);  // 0.5 MB f32 (B*L, 32)
  u16*  WxRaw = (u16*)(ws + 93 * MB);    //  8 MB bf16 W_x[:,32:] row-major
  u16*  W_cT  = (u16*)(ws + 101 * MB);   //  8 MB bf16 combined weight (N,K)
  u16*  dlt   = (u16*)(ws + 109 * MB);   // 16 MB bf16 (B*L, DINNER)
  float* Pc   = (float*)(ws + 141 * MB); //  8 MB
  float* Qc   = (float*)(ws + 149 * MB); //  8 MB
  float* Hs   = (float*)(ws + 157 * MB); //  8 MB
  float* bcp  = (float*)(ws + 165 * MB); //  8 MB split-K partials
  u16*  WxBCT = (u16*)(ws + 173 * MB);   // 128 KB bf16 (32,2048)
  u16*  yg    = (u16*)(ws + 0 * MB);     // 16 MB bf16, aliases xt+xn (dead)

  dim3 tb(32, 8);
  for (int b = 0; b < 2; ++b)
    k_transpose_cvt<<<dim3(SEQL / 32, DMODEL / 32), tb, 0, stream>>>(
        x + (size_t)b * DMODEL * SEQL, xt + (size_t)b * SEQL * DMODEL, DMODEL, SEQL, 0);
  k_transpose_cvt<<<dim3(4096 / 32, 1024 / 32), tb, 0, stream>>>(W_in, WinT, 1024, 4096, 0);
  k_transpose_cvt<<<dim3(1, 2048 / 32), tb, 0, stream>>>(W_x, WxBCT, 2048, 2080, 0);
  k_transpose_cvt<<<dim3(2048 / 32, 2048 / 32), tb, 0, stream>>>(W_dt, WdtT, 2048, 2048, 0);
  k_transpose_cvt<<<dim3(1024 / 32, 2048 / 32), tb, 0, stream>>>(W_out, WoutT, 2048, 1024, 0);
  k_cvt_rows<<<4096, 256, 0, stream>>>(W_x, WxRaw);

  // W_cT[n,k] = (Wx' @ W_dt)[k,n] : A=WdtT, BT=WxRaw; 128^2 tiles, grid 256
  gemm8p<1><<<256, 256, 0, stream>>>(WdtT, WxRaw, W_cT, nullptr, nullptr, 2048, 2048, 2048);

  k_layernorm<<<4096, 256, 0, stream>>>(xt, ln_w, ln_b, xn);

  // xz = xn @ W_in   (4096 x 4096, K=1024); 256^2 8-phase, grid 256 (chip-full)
  gemm8x<<<256, 512, 0, stream>>>(xn, WinT, xz, 4096, 4096, 1024);

  k_conv_silu<<<16384, 256, 0, stream>>>(xz, conv_w, conv_b, xbt);

  // bc = xbt @ W_x[:, :32]
  k_bc_mfma<<<dim3(4096 / 128, KS), 256, 0, stream>>>(xbt, WxBCT, bcp);
  k_bc_red<<<131072 / 256, 256, 0, stream>>>(bcp, bc);

  // dlt = softplus(xbt @ W_c + b_dt)  (bf16 out); 128^2, grid 512
  gemm8p<2><<<512, 256, 0, stream>>>(xbt, W_cT, dlt, b_dt, nullptr, 4096, 2048, 2048);

  // chunked scan
  k_scan_p1<<<dim3(DINNER / 256, NC, 2), 256, 0, stream>>>(dlt, xbt, bc, A_log, Pc, Qc);
  k_scan_p2<<<256, 256, 0, stream>>>(Pc, Qc, Hs);
  k_scan_p3<<<dim3(DINNER / 256, NC, 2), 256, 0, stream>>>(
      dlt, xbt, bc, xz, A_log, Dskip, Hs, yg);

  // out = yg @ W_out, transposed + residual; 128^2, grid 256
  gemm8p<3><<<256, 256, 0, stream>>>(yg, WoutT, out, nullptr, x, 4096, 1024, 2048);
}